// Round 9
// baseline (456.304 us; speedup 1.0000x reference)
//
#include <hip/hip_runtime.h>
#include <cstdint>

// GraphNets v9 = v8 + {768-thr blocks (12 waves/CU), W3 via L1, P slot-XOR,
// next-tile index prefetch}.
// mfma_f32_16x16x32_bf16: A lane l: row=l&15, k=(l>>4)*8+j ; B: col=l&15, same k
// C/D: col=lane&15, row=(lane>>4)*4+reg   [verified v2-v8]

typedef short short8 __attribute__((ext_vector_type(8)));
typedef float f32x4 __attribute__((ext_vector_type(4)));

#define MFMA16(a, b, c) __builtin_amdgcn_mfma_f32_16x16x32_bf16(a, b, c, 0, 0, 0)

__device__ __forceinline__ short f2bf(float x) {
    union { __bf16 b; short s; } u; u.b = (__bf16)x; return u.s;
}
__device__ __forceinline__ short8 pack8(float4 lo, float4 hi) {
    short8 r;
    r[0] = f2bf(lo.x); r[1] = f2bf(lo.y); r[2] = f2bf(lo.z); r[3] = f2bf(lo.w);
    r[4] = f2bf(hi.x); r[5] = f2bf(hi.y); r[6] = f2bf(hi.z); r[7] = f2bf(hi.w);
    return r;
}
__device__ __forceinline__ short8 pack8v(f32x4 lo, f32x4 hi) {
    short8 r;
    r[0] = f2bf(lo[0]); r[1] = f2bf(lo[1]); r[2] = f2bf(lo[2]); r[3] = f2bf(lo[3]);
    r[4] = f2bf(hi[0]); r[5] = f2bf(hi[1]); r[6] = f2bf(hi[2]); r[7] = f2bf(hi[3]);
    return r;
}

// ---------------------------------------------------------------------------
// Weight prep (verified v2-v8). Layout in ws:
//   We1 0 (64K) | We2 65536 (32K) | We3 98304 (16K) | Wn1 114688 (48K) |
//   Wn2 163840 (32K) | Wn3 196608 (16K)
// Edge kernel stages We1|We2 (contiguous 96K) to LDS, reads We3 from global.
// ---------------------------------------------------------------------------
__global__ __launch_bounds__(256)
void prep_weights(const float* __restrict__ We1, const float* __restrict__ We2,
                  const float* __restrict__ We3, const float* __restrict__ Wn1,
                  const float* __restrict__ Wn2, const float* __restrict__ Wn3,
                  char* __restrict__ out)
{
    const int fg = blockIdx.x * 4 + (threadIdx.x >> 6);
    if (fg >= 208) return;
    const int lane = threadIdx.x & 63;
    const float* W; int Ncols, f; size_t obase;
    if      (fg < 64)  { W = We1; Ncols = 128; f = fg;       obase = 0;      }
    else if (fg < 96)  { W = We2; Ncols = 128; f = fg - 64;  obase = 65536;  }
    else if (fg < 112) { W = We3; Ncols = 64;  f = fg - 96;  obase = 98304;  }
    else if (fg < 160) { W = Wn1; Ncols = 128; f = fg - 112; obase = 114688; }
    else if (fg < 192) { W = Wn2; Ncols = 128; f = fg - 160; obase = 163840; }
    else               { W = Wn3; Ncols = 64;  f = fg - 192; obase = 196608; }
    const int NF = Ncols >> 4;
    const int kf = f / NF, nf = f - kf * NF;
    const int k0 = kf * 32 + (lane >> 4) * 8;
    const int col = nf * 16 + (lane & 15);
    union { short s[8]; uint4 u; } pk;
#pragma unroll
    for (int j = 0; j < 8; ++j) pk.s[j] = f2bf(W[(size_t)(k0 + j) * Ncols + col]);
    *(uint4*)(out + obase + ((size_t)f * 64 + lane) * 16) = pk.u;
}

// ---------------------------------------------------------------------------
// CSR build (verified v4)
// ---------------------------------------------------------------------------
__global__ __launch_bounds__(256)
void hist_kernel(const int* __restrict__ dst, int* __restrict__ deg, int E)
{
    const int i = blockIdx.x * 256 + threadIdx.x;
    if (i < E) atomicAdd(&deg[dst[i]], 1);
}
__global__ __launch_bounds__(256)
void scanA_kernel(const int* __restrict__ deg, int* __restrict__ psum, int n)
{
    __shared__ int red[256];
    const int t = threadIdx.x;
    const int i = blockIdx.x * 256 + t;
    red[t] = (i < n) ? deg[i] : 0;
    __syncthreads();
    for (int s = 128; s > 0; s >>= 1) {
        if (t < s) red[t] += red[t + s];
        __syncthreads();
    }
    if (t == 0) psum[blockIdx.x] = red[0];
}
__global__ __launch_bounds__(256)
void scanB_kernel(int* __restrict__ psum, int nb)
{
    __shared__ int s[256];
    const int t = threadIdx.x;
    const int v0 = (t < nb) ? psum[t] : 0;
    s[t] = v0;
    __syncthreads();
    for (int d = 1; d < 256; d <<= 1) {
        const int v = (t >= d) ? s[t - d] : 0;
        __syncthreads();
        s[t] += v;
        __syncthreads();
    }
    if (t < nb) psum[t] = s[t] - v0;
}
__global__ __launch_bounds__(256)
void scanC_kernel(const int* __restrict__ deg, const int* __restrict__ psum,
                  int* __restrict__ start, int* __restrict__ cursor, int n)
{
    __shared__ int s[256];
    const int t = threadIdx.x;
    const int i = blockIdx.x * 256 + t;
    const int v0 = (i < n) ? deg[i] : 0;
    s[t] = v0;
    __syncthreads();
    for (int d = 1; d < 256; d <<= 1) {
        const int v = (t >= d) ? s[t - d] : 0;
        __syncthreads();
        s[t] += v;
        __syncthreads();
    }
    const int ex = s[t] - v0 + psum[blockIdx.x];
    if (i < n) { start[i] = ex; cursor[i] = ex; }
}
__global__ __launch_bounds__(256)
void fill_kernel(const int* __restrict__ dst, int* __restrict__ cursor,
                 int* __restrict__ elist, int E)
{
    const int i = blockIdx.x * 256 + threadIdx.x;
    if (i < E) {
        const int d = dst[i];
        const int p = atomicAdd(&cursor[d], 1);
        elist[p] = i;
    }
}

// ---------------------------------------------------------------------------
// Fused MLP (v8 structure), 768 thr = 12 waves, 1 block/CU, 192-row tiles.
// W1|W2 in LDS; W3 from global (L1-resident, 16 KB shared by all waves).
// comb: per-wave one-hot MFMA into registers; P staging slot-XOR'd.
// ---------------------------------------------------------------------------
template <int NQ, bool IS_EDGE, bool MSG_ATOMIC, bool GATHER>
__global__ __launch_bounds__(768, 3)
void mlp_fused_kernel(const float* __restrict__ feat0,
                      const float* feat1,
                      const float* __restrict__ gr,
                      const int* __restrict__ srcIdx, const int* __restrict__ dstIdx,
                      const int* __restrict__ seg,
                      const int* __restrict__ gstart, const int* __restrict__ gend,
                      const int* __restrict__ elist,  const float* __restrict__ gsrc,
                      const char* __restrict__ Wsrc,  const char* __restrict__ W3g,
                      const float* __restrict__ b1, const float* __restrict__ b2,
                      const float* __restrict__ b3,
                      float* out, float* msgs_out, float* comb_rep,
                      int M, int ntiles)
{
    constexpr int KF1   = NQ * 2;                  // layer-1 kf count
    constexpr int NFRAG = KF1 * 8 + 32;            // W1 + W2 frags (LDS)
    constexpr int HOFF  = NFRAG * 1024;
    constexpr int NW    = 12;                      // waves per block
    extern __shared__ char lds[];
    float* combs = (float*)(lds + HOFF + NW * 4096);

    const int t    = threadIdx.x;
    const int lane = t & 63;
    const int w    = t >> 6;
    const int l15  = lane & 15;
    const int l4   = lane >> 4;
    char* Hs = lds + HOFF + w * 4096;              // wave-private 4KB (h1/h2/P)

    // ---- stage W1|W2 fragments to LDS once; zero comb ----
    for (int f = t; f < NFRAG * 64; f += 768)
        *(uint4*)(lds + (size_t)f * 16) = *(const uint4*)(Wsrc + (size_t)f * 16);
    for (int i = t; i < 1024; i += 768) combs[i] = 0.f;
    __syncthreads();

    const char* W1l = lds;
    const char* W2l = lds + (size_t)KF1 * 8 * 1024;

    // per-wave comb accumulators: acc_comb[nf][q] -> graph g=l4*4+q, col nf*16+l15
    f32x4 acc_comb[4];
#pragma unroll
    for (int nf = 0; nf < 4; ++nf) acc_comb[nf] = f32x4{0.f, 0.f, 0.f, 0.f};

    // ---- index prefetch state (this lane's row of the upcoming tile) ----
    int pi_src = 0, pi_dst = 0, pi_g = 0;
    bool pvalid = false;
    {
        const int row = blockIdx.x * (NW * 16) + w * 16 + l15;
        pvalid = row < M;
        if (pvalid) {
            if (IS_EDGE) { pi_src = srcIdx[row]; pi_dst = dstIdx[row]; pi_g = seg[row]; }
            else         { pi_g = seg[row]; }
        }
    }

    for (int tile = blockIdx.x; tile < ntiles; tile += gridDim.x) {
        const int base  = tile * (NW * 16) + w * 16;
        const int row   = base + l15;
        const bool valid = pvalid;
        const int isrc = pi_src, idst = pi_dst, ig = pi_g;

        // ---- gather X straight into A-fragment registers ----
        short8 xf[KF1];
#pragma unroll
        for (int kf = 0; kf < KF1; ++kf) {
            const int c = kf >> 1;
            if (GATHER && c == 1) continue;        // msgs handled below
            float4 lo = make_float4(0.f, 0.f, 0.f, 0.f), hi = lo;
            if (valid) {
                const float* p;
                if (IS_EDGE) {
                    p = (c == 0) ? feat0 + (size_t)row  * 64
                      : (c == 1) ? feat1 + (size_t)isrc * 64
                      : (c == 2) ? feat1 + (size_t)idst * 64
                      :            gr    + (size_t)ig   * 64;
                } else if (GATHER) {
                    p = (c == 0) ? feat0 + (size_t)row * 64
                      :            gr    + (size_t)ig  * 64;
                } else {
                    p = (c == 0) ? feat0 + (size_t)row * 64
                      : (c == 1) ? feat1 + (size_t)row * 64
                      :            gr    + (size_t)ig  * 64;
                }
                const int koff = (kf & 1) * 32 + l4 * 8;
                lo = *(const float4*)(p + koff);
                hi = *(const float4*)(p + koff + 4);
            }
            xf[kf] = pack8(lo, hi);
        }
        if constexpr (GATHER) {
            f32x4 m0 = {0,0,0,0}, m1 = m0, m2 = m0, m3 = m0;
            if (valid) {
                const int s0 = gstart[row], e0 = gend[row];
                for (int j = s0; j < e0; ++j) {
                    const float* er = gsrc + (size_t)elist[j] * 64 + l4 * 8;
                    m0 += *(const f32x4*)(er);
                    m1 += *(const f32x4*)(er + 4);
                    m2 += *(const f32x4*)(er + 32);
                    m3 += *(const f32x4*)(er + 36);
                }
            }
            xf[2] = pack8v(m0, m1);
            xf[3] = pack8v(m2, m3);
        }

        // ---- prefetch next tile's indices (hides idx->feature dep chain) ----
        {
            const int nrow = (tile + gridDim.x) * (NW * 16) + w * 16 + l15;
            pvalid = (tile + gridDim.x < ntiles) && (nrow < M);
            if (pvalid) {
                if (IS_EDGE) { pi_src = srcIdx[nrow]; pi_dst = dstIdx[nrow]; pi_g = seg[nrow]; }
                else         { pi_g = seg[nrow]; }
            }
        }

        // ---- layer 1 ----
        f32x4 acc[8];
#pragma unroll
        for (int nf = 0; nf < 8; ++nf) {
            const float bv = b1[nf * 16 + l15];
            acc[nf] = f32x4{bv, bv, bv, bv};
        }
#pragma unroll
        for (int kf = 0; kf < KF1; ++kf) {
#pragma unroll
            for (int nf = 0; nf < 8; ++nf) {
                short8 bw = *(const short8*)(W1l + ((size_t)(kf * 8 + nf) * 64 + lane) * 16);
                acc[nf] = MFMA16(xf[kf], bw, acc[nf]);
            }
        }
        // relu -> h1 (wave-private swizzle, stride 256B)
#pragma unroll
        for (int nf = 0; nf < 8; ++nf)
#pragma unroll
            for (int q = 0; q < 4; ++q) {
                const int rowL = l4 * 4 + q;
                const int slot = (nf * 2 + (l15 >> 3)) ^ (rowL & 7);
                *(short*)(Hs + rowL * 256 + slot * 16 + (l15 & 7) * 2) =
                    f2bf(fmaxf(acc[nf][q], 0.f));
            }

        // ---- layer 2 ----
        f32x4 acc2[8];
#pragma unroll
        for (int nf = 0; nf < 8; ++nf) {
            const float bv = b2[nf * 16 + l15];
            acc2[nf] = f32x4{bv, bv, bv, bv};
        }
#pragma unroll
        for (int kf = 0; kf < 4; ++kf) {
            const int slot = (kf * 4 + l4) ^ (l15 & 7);
            short8 a = *(short8*)(Hs + l15 * 256 + slot * 16);
#pragma unroll
            for (int nf = 0; nf < 8; ++nf) {
                short8 bw = *(const short8*)(W2l + ((size_t)(kf * 8 + nf) * 64 + lane) * 16);
                acc2[nf] = MFMA16(a, bw, acc2[nf]);
            }
        }
        // relu -> h2 (aliases h1; in-wave DS order makes this safe)
#pragma unroll
        for (int nf = 0; nf < 8; ++nf)
#pragma unroll
            for (int q = 0; q < 4; ++q) {
                const int rowL = l4 * 4 + q;
                const int slot = (nf * 2 + (l15 >> 3)) ^ (rowL & 7);
                *(short*)(Hs + rowL * 256 + slot * 16 + (l15 & 7) * 2) =
                    f2bf(fmaxf(acc2[nf][q], 0.f));
            }

        // ---- layer 3 (W3 from global; identical addr across waves -> L1) ----
        f32x4 acc3[4];
#pragma unroll
        for (int nf = 0; nf < 4; ++nf) {
            const float bv = b3[nf * 16 + l15];
            acc3[nf] = f32x4{bv, bv, bv, bv};
        }
#pragma unroll
        for (int kf = 0; kf < 4; ++kf) {
            const int slot = (kf * 4 + l4) ^ (l15 & 7);
            short8 a = *(short8*)(Hs + l15 * 256 + slot * 16);
#pragma unroll
            for (int nf = 0; nf < 4; ++nf) {
                short8 bw = *(const short8*)(W3g + ((size_t)(kf * 4 + nf) * 64 + lane) * 16);
                acc3[nf] = MFMA16(a, bw, acc3[nf]);
            }
        }

        // ---- comb via one-hot MFMA; P staged with slot-XOR (bank fix) ----
        // P[col][rows 0..15], 64B/col; logical 16B slot s at physical s^(col&3).
#pragma unroll
        for (int nf = 0; nf < 4; ++nf) {
            union { unsigned u; short s[2]; } p01, p23;
            p01.s[0] = f2bf(acc3[nf][0]); p01.s[1] = f2bf(acc3[nf][1]);
            p23.s[0] = f2bf(acc3[nf][2]); p23.s[1] = f2bf(acc3[nf][3]);
            const int col = nf * 16 + l15;
            const int sw  = ((l4 >> 1) ^ (col & 3));
            char* pc = Hs + col * 64 + sw * 16 + (l4 & 1) * 8;
            *(unsigned*)(pc)     = p01.u;
            *(unsigned*)(pc + 4) = p23.u;
        }
        // One-hot A: lane l -> g=l15, k=l4*8+j; k>=16 lanes contribute 0.
        short8 oh;
#pragma unroll
        for (int j = 0; j < 8; ++j) {
            short v = 0;
            if (l4 < 2) {
                const int rr = base + l4 * 8 + j;
                if (rr < M && seg[rr] == l15) v = (short)0x3F80;  // bf16 1.0
            }
            oh[j] = v;
        }
#pragma unroll
        for (int nf = 0; nf < 4; ++nf) {
            const int col = nf * 16 + l15;
            const int sr  = l4 ^ (col & 3);
            short8 bp = *(short8*)(Hs + col * 64 + sr * 16);
            acc_comb[nf] = MFMA16(oh, bp, acc_comb[nf]);
        }

        // ---- epilogue: store out (+ fallback msgs atomics) ----
#pragma unroll
        for (int q = 0; q < 4; ++q) {
            const int grow = base + l4 * 4 + q;
            if (grow < M) {
                int d = 0;
                if (MSG_ATOMIC) d = dstIdx[grow];
#pragma unroll
                for (int nf = 0; nf < 4; ++nf) {
                    const int col = nf * 16 + l15;
                    const float v = acc3[nf][q];
                    out[(size_t)grow * 64 + col] = v;
                    if constexpr (MSG_ATOMIC)
                        atomicAdd(msgs_out + (size_t)d * 64 + col, v);
                }
            }
        }
    }

    // ---- flush: acc_comb -> block comb (once), then to global replica ----
#pragma unroll
    for (int nf = 0; nf < 4; ++nf)
#pragma unroll
        for (int q = 0; q < 4; ++q)
            atomicAdd(&combs[(l4 * 4 + q) * 64 + nf * 16 + l15], acc_comb[nf][q]);
    __syncthreads();
    float* rep = comb_rep + (size_t)(blockIdx.x & 63) * 1024;
    for (int i = t; i < 1024; i += 768) atomicAdd(rep + i, combs[i]);
}

// ---------------------------------------------------------------------------
__global__ __launch_bounds__(256)
void reduce_rep_kernel(const float* __restrict__ rep, float* __restrict__ outv)
{
    const int s = blockIdx.x * 256 + threadIdx.x;   // 0..2047
    const int arr = s >> 10, idx = s & 1023;
    const float* p = rep + (size_t)arr * 65536 + idx;
    float v = 0.f;
#pragma unroll 8
    for (int r = 0; r < 64; ++r) v += p[(size_t)r * 1024];
    outv[s] = v;
}

// ---------------------------------------------------------------------------
__global__ __launch_bounds__(256)
void u_kernel(const float* __restrict__ ncomb, const float* __restrict__ ecomb,
              const float* __restrict__ gr,
              const float* __restrict__ W1, const float* __restrict__ b1,
              const float* __restrict__ W2, const float* __restrict__ b2,
              const float* __restrict__ W3, const float* __restrict__ b3,
              float* uout)
{
    __shared__ float X[16 * 192];
    __shared__ float Hs[16 * 128];
    __shared__ float H2s[16 * 128];
    const int t = threadIdx.x;
#pragma unroll
    for (int i = 0; i < 12; ++i) {
        const int idx = i * 256 + t;
        const int g = idx / 192, col = idx % 192;
        float v;
        if      (col < 64)  v = ncomb[g * 64 + col];
        else if (col < 128) v = ecomb[g * 64 + col - 64];
        else                v = gr[g * 64 + col - 128];
        X[idx] = v;
    }
    __syncthreads();
    {
        const int j = t & 127, gb = t >> 7;
        float a[8];
#pragma unroll
        for (int gi = 0; gi < 8; ++gi) a[gi] = b1[j];
        for (int k = 0; k < 192; ++k) {
            const float wv = W1[k * 128 + j];
#pragma unroll
            for (int gi = 0; gi < 8; ++gi) a[gi] += X[(gb + gi * 2) * 192 + k] * wv;
        }
#pragma unroll
        for (int gi = 0; gi < 8; ++gi) Hs[(gb + gi * 2) * 128 + j] = fmaxf(a[gi], 0.f);
    }
    __syncthreads();
    {
        const int j = t & 127, gb = t >> 7;
        float a[8];
#pragma unroll
        for (int gi = 0; gi < 8; ++gi) a[gi] = b2[j];
        for (int k = 0; k < 128; ++k) {
            const float wv = W2[k * 128 + j];
#pragma unroll
            for (int gi = 0; gi < 8; ++gi) a[gi] += Hs[(gb + gi * 2) * 128 + k] * wv;
        }
#pragma unroll
        for (int gi = 0; gi < 8; ++gi) H2s[(gb + gi * 2) * 128 + j] = fmaxf(a[gi], 0.f);
    }
    __syncthreads();
    {
        const int j = t & 63, gb = t >> 6;
        float a[4];
#pragma unroll
        for (int gi = 0; gi < 4; ++gi) a[gi] = b3[j];
        for (int k = 0; k < 128; ++k) {
            const float wv = W3[k * 64 + j];
#pragma unroll
            for (int gi = 0; gi < 4; ++gi) a[gi] += H2s[(gb + gi * 4) * 128 + k] * wv;
        }
#pragma unroll
        for (int gi = 0; gi < 4; ++gi) uout[(gb + gi * 4) * 64 + j] = a[gi];
    }
}

// ---------------------------------------------------------------------------
extern "C" void kernel_launch(void* const* d_in, const int* in_sizes, int n_in,
                              void* d_out, int out_size, void* d_ws, size_t ws_size,
                              hipStream_t stream)
{
    const float* edge_feat = (const float*)d_in[0];
    const float* node_feat = (const float*)d_in[1];
    const float* g_repr    = (const float*)d_in[2];
    const int*   src       = (const int*)d_in[3];
    const int*   dst       = (const int*)d_in[4];
    const int*   e2g       = (const int*)d_in[5];
    const int*   n2g       = (const int*)d_in[6];
    const float* We1 = (const float*)d_in[7];  const float* be1 = (const float*)d_in[8];
    const float* We2 = (const float*)d_in[9];  const float* be2 = (const float*)d_in[10];
    const float* We3 = (const float*)d_in[11]; const float* be3 = (const float*)d_in[12];
    const float* Wn1 = (const float*)d_in[13]; const float* bn1 = (const float*)d_in[14];
    const float* Wn2 = (const float*)d_in[15]; const float* bn2 = (const float*)d_in[16];
    const float* Wn3 = (const float*)d_in[17]; const float* bn3 = (const float*)d_in[18];
    const float* Wu1 = (const float*)d_in[19]; const float* bu1 = (const float*)d_in[20];
    const float* Wu2 = (const float*)d_in[21]; const float* bu2 = (const float*)d_in[22];
    const float* Wu3 = (const float*)d_in[23]; const float* bu3 = (const float*)d_in[24];

    const int E = in_sizes[3];   // 400000
    const int N = in_sizes[6];   // 50000

    float* e_out = (float*)d_out;
    float* n_out = e_out + (size_t)E * 64;
    float* u_out = n_out + (size_t)N * 64;

    char* wsc = (char*)d_ws;
    float* ecomb_rep = (float*)wsc;
    float* ncomb_rep = (float*)(wsc + 262144);
    float* ecomb     = (float*)(wsc + 524288);
    float* ncomb     = ecomb + 1024;
    char*  wf        = wsc + 532480;
    const char* WEsrc = wf;              // We1|We2 (96 KB, LDS-staged)
    const char* We3f  = wf + 98304;      // We3 (16 KB, L1)
    const char* WNsrc = wf + 114688;     // Wn1|Wn2 (80 KB, LDS-staged)
    const char* Wn3f  = wf + 196608;     // Wn3 (16 KB, L1)
    int* deg    = (int*)(wsc + 745472);
    int* startA = (int*)(wsc + 945472);
    int* cursor = (int*)(wsc + 1145472);
    int* psum   = (int*)(wsc + 1345472);
    int* elist  = (int*)(wsc + 1346496);
    const size_t WS_NEED = 1346496 + (size_t)E * 4;
    const bool csr = (ws_size >= WS_NEED);

    constexpr int SH_E = (96 + 48 + 4) * 1024;   // 151552
    constexpr int SH_N = (80 + 48 + 4) * 1024;   // 135168

    hipMemsetAsync(wsc, 0, 524288, stream);
    prep_weights<<<52, 256, 0, stream>>>(We1, We2, We3, Wn1, Wn2, Wn3, wf);

    const int etiles = (E + 191) / 192;
    const int ntiles = (N + 191) / 192;

    if (csr) {
        hipMemsetAsync(deg, 0, (size_t)N * 4, stream);
        const int EB = (E + 255) / 256;
        const int NB = (N + 255) / 256;
        hist_kernel <<<EB, 256, 0, stream>>>(dst, deg, E);
        scanA_kernel<<<NB, 256, 0, stream>>>(deg, psum, N);
        scanB_kernel<<<1, 256, 0, stream>>>(psum, NB);
        scanC_kernel<<<NB, 256, 0, stream>>>(deg, psum, startA, cursor, N);
        fill_kernel <<<EB, 256, 0, stream>>>(dst, cursor, elist, E);

        auto ek = mlp_fused_kernel<4, true, false, false>;
        auto nk = mlp_fused_kernel<3, false, false, true>;
        hipFuncSetAttribute((const void*)ek,
                            hipFuncAttributeMaxDynamicSharedMemorySize, SH_E);
        hipFuncSetAttribute((const void*)nk,
                            hipFuncAttributeMaxDynamicSharedMemorySize, SH_N);

        ek<<<256, 768, SH_E, stream>>>(
            edge_feat, node_feat, g_repr, src, dst, e2g,
            nullptr, nullptr, nullptr, nullptr,
            WEsrc, We3f, be1, be2, be3, e_out, nullptr, ecomb_rep, E, etiles);
        nk<<<256, 768, SH_N, stream>>>(
            node_feat, nullptr, g_repr, nullptr, nullptr, n2g,
            startA, cursor, elist, e_out,
            WNsrc, Wn3f, bn1, bn2, bn3, n_out, nullptr, ncomb_rep, N, ntiles);
    } else {
        hipMemsetAsync(n_out, 0, (size_t)N * 64 * sizeof(float), stream);
        auto ek = mlp_fused_kernel<4, true, true, false>;
        auto nk = mlp_fused_kernel<3, false, false, false>;
        hipFuncSetAttribute((const void*)ek,
                            hipFuncAttributeMaxDynamicSharedMemorySize, SH_E);
        hipFuncSetAttribute((const void*)nk,
                            hipFuncAttributeMaxDynamicSharedMemorySize, SH_N);
        ek<<<256, 768, SH_E, stream>>>(
            edge_feat, node_feat, g_repr, src, dst, e2g,
            nullptr, nullptr, nullptr, nullptr,
            WEsrc, We3f, be1, be2, be3, e_out, n_out, ecomb_rep, E, etiles);
        nk<<<256, 768, SH_N, stream>>>(
            node_feat, n_out, g_repr, nullptr, nullptr, n2g,
            nullptr, nullptr, nullptr, nullptr,
            WNsrc, Wn3f, bn1, bn2, bn3, n_out, nullptr, ncomb_rep, N, ntiles);
    }

    reduce_rep_kernel<<<8, 256, 0, stream>>>(ecomb_rep, ecomb);
    u_kernel<<<1, 256, 0, stream>>>(ncomb, ecomb, g_repr,
                                    Wu1, bu1, Wu2, bu2, Wu3, bu3, u_out);
}

// Round 10
// 331.298 us; speedup vs baseline: 1.3773x; 1.3773x over previous
//
#include <hip/hip_runtime.h>
#include <cstdint>

// GraphNets v10 = v9 (768 thr, 12 waves, P slot-XOR, idx prefetch) but with
// ALL weights (W1|W2|W3) in LDS and comb reduced via register->Hs-slice tree
// (no LDS comb array). LDS = 112K + 12*4K = 160 KB exactly (edge).
// mfma_f32_16x16x32_bf16: A lane l: row=l&15, k=(l>>4)*8+j ; B: col=l&15, same k
// C/D: col=lane&15, row=(lane>>4)*4+reg   [verified v2-v9]

typedef short short8 __attribute__((ext_vector_type(8)));
typedef float f32x4 __attribute__((ext_vector_type(4)));

#define MFMA16(a, b, c) __builtin_amdgcn_mfma_f32_16x16x32_bf16(a, b, c, 0, 0, 0)

__device__ __forceinline__ short f2bf(float x) {
    union { __bf16 b; short s; } u; u.b = (__bf16)x; return u.s;
}
__device__ __forceinline__ short8 pack8(float4 lo, float4 hi) {
    short8 r;
    r[0] = f2bf(lo.x); r[1] = f2bf(lo.y); r[2] = f2bf(lo.z); r[3] = f2bf(lo.w);
    r[4] = f2bf(hi.x); r[5] = f2bf(hi.y); r[6] = f2bf(hi.z); r[7] = f2bf(hi.w);
    return r;
}
__device__ __forceinline__ short8 pack8v(f32x4 lo, f32x4 hi) {
    short8 r;
    r[0] = f2bf(lo[0]); r[1] = f2bf(lo[1]); r[2] = f2bf(lo[2]); r[3] = f2bf(lo[3]);
    r[4] = f2bf(hi[0]); r[5] = f2bf(hi[1]); r[6] = f2bf(hi[2]); r[7] = f2bf(hi[3]);
    return r;
}

// ---------------------------------------------------------------------------
// Weight prep (verified v2-v9). edge = We1|We2|We3 contiguous 112KB at 0,
// node = Wn1|Wn2|Wn3 contiguous 96KB at 114688.
// ---------------------------------------------------------------------------
__global__ __launch_bounds__(256)
void prep_weights(const float* __restrict__ We1, const float* __restrict__ We2,
                  const float* __restrict__ We3, const float* __restrict__ Wn1,
                  const float* __restrict__ Wn2, const float* __restrict__ Wn3,
                  char* __restrict__ out)
{
    const int fg = blockIdx.x * 4 + (threadIdx.x >> 6);
    if (fg >= 208) return;
    const int lane = threadIdx.x & 63;
    const float* W; int Ncols, f; size_t obase;
    if      (fg < 64)  { W = We1; Ncols = 128; f = fg;       obase = 0;      }
    else if (fg < 96)  { W = We2; Ncols = 128; f = fg - 64;  obase = 65536;  }
    else if (fg < 112) { W = We3; Ncols = 64;  f = fg - 96;  obase = 98304;  }
    else if (fg < 160) { W = Wn1; Ncols = 128; f = fg - 112; obase = 114688; }
    else if (fg < 192) { W = Wn2; Ncols = 128; f = fg - 160; obase = 163840; }
    else               { W = Wn3; Ncols = 64;  f = fg - 192; obase = 196608; }
    const int NF = Ncols >> 4;
    const int kf = f / NF, nf = f - kf * NF;
    const int k0 = kf * 32 + (lane >> 4) * 8;
    const int col = nf * 16 + (lane & 15);
    union { short s[8]; uint4 u; } pk;
#pragma unroll
    for (int j = 0; j < 8; ++j) pk.s[j] = f2bf(W[(size_t)(k0 + j) * Ncols + col]);
    *(uint4*)(out + obase + ((size_t)f * 64 + lane) * 16) = pk.u;
}

// ---------------------------------------------------------------------------
// CSR build (verified v4)
// ---------------------------------------------------------------------------
__global__ __launch_bounds__(256)
void hist_kernel(const int* __restrict__ dst, int* __restrict__ deg, int E)
{
    const int i = blockIdx.x * 256 + threadIdx.x;
    if (i < E) atomicAdd(&deg[dst[i]], 1);
}
__global__ __launch_bounds__(256)
void scanA_kernel(const int* __restrict__ deg, int* __restrict__ psum, int n)
{
    __shared__ int red[256];
    const int t = threadIdx.x;
    const int i = blockIdx.x * 256 + t;
    red[t] = (i < n) ? deg[i] : 0;
    __syncthreads();
    for (int s = 128; s > 0; s >>= 1) {
        if (t < s) red[t] += red[t + s];
        __syncthreads();
    }
    if (t == 0) psum[blockIdx.x] = red[0];
}
__global__ __launch_bounds__(256)
void scanB_kernel(int* __restrict__ psum, int nb)
{
    __shared__ int s[256];
    const int t = threadIdx.x;
    const int v0 = (t < nb) ? psum[t] : 0;
    s[t] = v0;
    __syncthreads();
    for (int d = 1; d < 256; d <<= 1) {
        const int v = (t >= d) ? s[t - d] : 0;
        __syncthreads();
        s[t] += v;
        __syncthreads();
    }
    if (t < nb) psum[t] = s[t] - v0;
}
__global__ __launch_bounds__(256)
void scanC_kernel(const int* __restrict__ deg, const int* __restrict__ psum,
                  int* __restrict__ start, int* __restrict__ cursor, int n)
{
    __shared__ int s[256];
    const int t = threadIdx.x;
    const int i = blockIdx.x * 256 + t;
    const int v0 = (i < n) ? deg[i] : 0;
    s[t] = v0;
    __syncthreads();
    for (int d = 1; d < 256; d <<= 1) {
        const int v = (t >= d) ? s[t - d] : 0;
        __syncthreads();
        s[t] += v;
        __syncthreads();
    }
    const int ex = s[t] - v0 + psum[blockIdx.x];
    if (i < n) { start[i] = ex; cursor[i] = ex; }
}
__global__ __launch_bounds__(256)
void fill_kernel(const int* __restrict__ dst, int* __restrict__ cursor,
                 int* __restrict__ elist, int E)
{
    const int i = blockIdx.x * 256 + threadIdx.x;
    if (i < E) {
        const int d = dst[i];
        const int p = atomicAdd(&cursor[d], 1);
        elist[p] = i;
    }
}

// ---------------------------------------------------------------------------
// Fused MLP: 768 thr = 12 waves, 1 block/CU, 192-row tiles, 16 rows/wave.
// W1|W2|W3 all LDS-resident. comb in registers, reduced via Hs slices at end.
// ---------------------------------------------------------------------------
template <int NQ, bool IS_EDGE, bool MSG_ATOMIC, bool GATHER>
__global__ __launch_bounds__(768, 3)
void mlp_fused_kernel(const float* __restrict__ feat0,
                      const float* feat1,
                      const float* __restrict__ gr,
                      const int* __restrict__ srcIdx, const int* __restrict__ dstIdx,
                      const int* __restrict__ seg,
                      const int* __restrict__ gstart, const int* __restrict__ gend,
                      const int* __restrict__ elist,  const float* __restrict__ gsrc,
                      const char* __restrict__ Wsrc,
                      const float* __restrict__ b1, const float* __restrict__ b2,
                      const float* __restrict__ b3,
                      float* out, float* msgs_out, float* comb_rep,
                      int M, int ntiles)
{
    constexpr int KF1   = NQ * 2;                  // layer-1 kf count
    constexpr int NFRAG = KF1 * 8 + 32 + 16;       // W1 + W2 + W3 frags (LDS)
    constexpr int HOFF  = NFRAG * 1024;
    constexpr int NW    = 12;                      // waves per block
    extern __shared__ char lds[];

    const int t    = threadIdx.x;
    const int lane = t & 63;
    const int w    = t >> 6;
    const int l15  = lane & 15;
    const int l4   = lane >> 4;
    char* Hs = lds + HOFF + w * 4096;              // wave-private 4KB (h1/h2/P)

    // ---- stage all weight fragments to LDS once ----
    for (int f = t; f < NFRAG * 64; f += 768)
        *(uint4*)(lds + (size_t)f * 16) = *(const uint4*)(Wsrc + (size_t)f * 16);
    __syncthreads();

    const char* W1l = lds;
    const char* W2l = lds + (size_t)KF1 * 8 * 1024;
    const char* W3l = W2l + 32 * 1024;

    // per-wave comb accumulators: acc_comb[nf][q] -> graph g=l4*4+q, col nf*16+l15
    f32x4 acc_comb[4];
#pragma unroll
    for (int nf = 0; nf < 4; ++nf) acc_comb[nf] = f32x4{0.f, 0.f, 0.f, 0.f};

    // ---- index prefetch state (this lane's row of the upcoming tile) ----
    int pi_src = 0, pi_dst = 0, pi_g = 0;
    bool pvalid = false;
    {
        const int row = blockIdx.x * (NW * 16) + w * 16 + l15;
        pvalid = row < M;
        if (pvalid) {
            if (IS_EDGE) { pi_src = srcIdx[row]; pi_dst = dstIdx[row]; pi_g = seg[row]; }
            else         { pi_g = seg[row]; }
        }
    }

    for (int tile = blockIdx.x; tile < ntiles; tile += gridDim.x) {
        const int base  = tile * (NW * 16) + w * 16;
        const int row   = base + l15;
        const bool valid = pvalid;
        const int isrc = pi_src, idst = pi_dst, ig = pi_g;
        (void)idst;

        // ---- gather X straight into A-fragment registers ----
        short8 xf[KF1];
#pragma unroll
        for (int kf = 0; kf < KF1; ++kf) {
            const int c = kf >> 1;
            if (GATHER && c == 1) continue;        // msgs handled below
            float4 lo = make_float4(0.f, 0.f, 0.f, 0.f), hi = lo;
            if (valid) {
                const float* p;
                if (IS_EDGE) {
                    p = (c == 0) ? feat0 + (size_t)row  * 64
                      : (c == 1) ? feat1 + (size_t)isrc * 64
                      : (c == 2) ? feat1 + (size_t)idst * 64
                      :            gr    + (size_t)ig   * 64;
                } else if (GATHER) {
                    p = (c == 0) ? feat0 + (size_t)row * 64
                      :            gr    + (size_t)ig  * 64;
                } else {
                    p = (c == 0) ? feat0 + (size_t)row * 64
                      : (c == 1) ? feat1 + (size_t)row * 64
                      :            gr    + (size_t)ig  * 64;
                }
                const int koff = (kf & 1) * 32 + l4 * 8;
                lo = *(const float4*)(p + koff);
                hi = *(const float4*)(p + koff + 4);
            }
            xf[kf] = pack8(lo, hi);
        }
        if constexpr (GATHER) {
            f32x4 m0 = {0,0,0,0}, m1 = m0, m2 = m0, m3 = m0;
            if (valid) {
                const int s0 = gstart[row], e0 = gend[row];
                for (int j = s0; j < e0; ++j) {
                    const float* er = gsrc + (size_t)elist[j] * 64 + l4 * 8;
                    m0 += *(const f32x4*)(er);
                    m1 += *(const f32x4*)(er + 4);
                    m2 += *(const f32x4*)(er + 32);
                    m3 += *(const f32x4*)(er + 36);
                }
            }
            xf[2] = pack8v(m0, m1);
            xf[3] = pack8v(m2, m3);
        }

        // ---- prefetch next tile's indices ----
        {
            const int nrow = (tile + gridDim.x) * (NW * 16) + w * 16 + l15;
            pvalid = (tile + gridDim.x < ntiles) && (nrow < M);
            if (pvalid) {
                if (IS_EDGE) { pi_src = srcIdx[nrow]; pi_dst = dstIdx[nrow]; pi_g = seg[nrow]; }
                else         { pi_g = seg[nrow]; }
            }
        }

        // ---- layer 1 ----
        f32x4 acc[8];
#pragma unroll
        for (int nf = 0; nf < 8; ++nf) {
            const float bv = b1[nf * 16 + l15];
            acc[nf] = f32x4{bv, bv, bv, bv};
        }
#pragma unroll
        for (int kf = 0; kf < KF1; ++kf) {
#pragma unroll
            for (int nf = 0; nf < 8; ++nf) {
                short8 bw = *(const short8*)(W1l + ((size_t)(kf * 8 + nf) * 64 + lane) * 16);
                acc[nf] = MFMA16(xf[kf], bw, acc[nf]);
            }
        }
        // relu -> h1 (wave-private swizzle, stride 256B)
#pragma unroll
        for (int nf = 0; nf < 8; ++nf)
#pragma unroll
            for (int q = 0; q < 4; ++q) {
                const int rowL = l4 * 4 + q;
                const int slot = (nf * 2 + (l15 >> 3)) ^ (rowL & 7);
                *(short*)(Hs + rowL * 256 + slot * 16 + (l15 & 7) * 2) =
                    f2bf(fmaxf(acc[nf][q], 0.f));
            }

        // ---- layer 2 ----
        f32x4 acc2[8];
#pragma unroll
        for (int nf = 0; nf < 8; ++nf) {
            const float bv = b2[nf * 16 + l15];
            acc2[nf] = f32x4{bv, bv, bv, bv};
        }
#pragma unroll
        for (int kf = 0; kf < 4; ++kf) {
            const int slot = (kf * 4 + l4) ^ (l15 & 7);
            short8 a = *(short8*)(Hs + l15 * 256 + slot * 16);
#pragma unroll
            for (int nf = 0; nf < 8; ++nf) {
                short8 bw = *(const short8*)(W2l + ((size_t)(kf * 8 + nf) * 64 + lane) * 16);
                acc2[nf] = MFMA16(a, bw, acc2[nf]);
            }
        }
        // relu -> h2 (aliases h1; in-wave DS order makes this safe)
#pragma unroll
        for (int nf = 0; nf < 8; ++nf)
#pragma unroll
            for (int q = 0; q < 4; ++q) {
                const int rowL = l4 * 4 + q;
                const int slot = (nf * 2 + (l15 >> 3)) ^ (rowL & 7);
                *(short*)(Hs + rowL * 256 + slot * 16 + (l15 & 7) * 2) =
                    f2bf(fmaxf(acc2[nf][q], 0.f));
            }

        // ---- layer 3 (W3 from LDS) ----
        f32x4 acc3[4];
#pragma unroll
        for (int nf = 0; nf < 4; ++nf) {
            const float bv = b3[nf * 16 + l15];
            acc3[nf] = f32x4{bv, bv, bv, bv};
        }
#pragma unroll
        for (int kf = 0; kf < 4; ++kf) {
            const int slot = (kf * 4 + l4) ^ (l15 & 7);
            short8 a = *(short8*)(Hs + l15 * 256 + slot * 16);
#pragma unroll
            for (int nf = 0; nf < 4; ++nf) {
                short8 bw = *(const short8*)(W3l + ((size_t)(kf * 4 + nf) * 64 + lane) * 16);
                acc3[nf] = MFMA16(a, bw, acc3[nf]);
            }
        }

        // ---- comb via one-hot MFMA; P staged with slot-XOR ----
#pragma unroll
        for (int nf = 0; nf < 4; ++nf) {
            union { unsigned u; short s[2]; } p01, p23;
            p01.s[0] = f2bf(acc3[nf][0]); p01.s[1] = f2bf(acc3[nf][1]);
            p23.s[0] = f2bf(acc3[nf][2]); p23.s[1] = f2bf(acc3[nf][3]);
            const int col = nf * 16 + l15;
            const int sw  = ((l4 >> 1) ^ (col & 3));
            char* pc = Hs + col * 64 + sw * 16 + (l4 & 1) * 8;
            *(unsigned*)(pc)     = p01.u;
            *(unsigned*)(pc + 4) = p23.u;
        }
        short8 oh;
#pragma unroll
        for (int j = 0; j < 8; ++j) {
            short v = 0;
            if (l4 < 2) {
                const int rr = base + l4 * 8 + j;
                if (rr < M && seg[rr] == l15) v = (short)0x3F80;  // bf16 1.0
            }
            oh[j] = v;
        }
#pragma unroll
        for (int nf = 0; nf < 4; ++nf) {
            const int col = nf * 16 + l15;
            const int sr  = l4 ^ (col & 3);
            short8 bp = *(short8*)(Hs + col * 64 + sr * 16);
            acc_comb[nf] = MFMA16(oh, bp, acc_comb[nf]);
        }

        // ---- epilogue: store out (+ fallback msgs atomics) ----
#pragma unroll
        for (int q = 0; q < 4; ++q) {
            const int grow = base + l4 * 4 + q;
            if (grow < M) {
                int d = 0;
                if (MSG_ATOMIC) d = dstIdx[grow];
#pragma unroll
                for (int nf = 0; nf < 4; ++nf) {
                    const int col = nf * 16 + l15;
                    const float v = acc3[nf][q];
                    out[(size_t)grow * 64 + col] = v;
                    if constexpr (MSG_ATOMIC)
                        atomicAdd(msgs_out + (size_t)d * 64 + col, v);
                }
            }
        }
    }

    // ---- flush: acc_comb -> own Hs slice -> cross-wave tree reduce ----
#pragma unroll
    for (int nf = 0; nf < 4; ++nf)
#pragma unroll
        for (int q = 0; q < 4; ++q)
            ((float*)Hs)[(l4 * 4 + q) * 64 + nf * 16 + l15] = acc_comb[nf][q];
    __syncthreads();
    float* hbase = (float*)(lds + HOFF);
    float* rep = comb_rep + (size_t)(blockIdx.x & 63) * 1024;
    for (int i = t; i < 1024; i += 768) {
        float s = 0.f;
#pragma unroll
        for (int wv = 0; wv < NW; ++wv) s += hbase[wv * 1024 + i];
        atomicAdd(rep + i, s);
    }
}

// ---------------------------------------------------------------------------
__global__ __launch_bounds__(256)
void reduce_rep_kernel(const float* __restrict__ rep, float* __restrict__ outv)
{
    const int s = blockIdx.x * 256 + threadIdx.x;   // 0..2047
    const int arr = s >> 10, idx = s & 1023;
    const float* p = rep + (size_t)arr * 65536 + idx;
    float v = 0.f;
#pragma unroll 8
    for (int r = 0; r < 64; ++r) v += p[(size_t)r * 1024];
    outv[s] = v;
}

// ---------------------------------------------------------------------------
__global__ __launch_bounds__(256)
void u_kernel(const float* __restrict__ ncomb, const float* __restrict__ ecomb,
              const float* __restrict__ gr,
              const float* __restrict__ W1, const float* __restrict__ b1,
              const float* __restrict__ W2, const float* __restrict__ b2,
              const float* __restrict__ W3, const float* __restrict__ b3,
              float* uout)
{
    __shared__ float X[16 * 192];
    __shared__ float Hs[16 * 128];
    __shared__ float H2s[16 * 128];
    const int t = threadIdx.x;
#pragma unroll
    for (int i = 0; i < 12; ++i) {
        const int idx = i * 256 + t;
        const int g = idx / 192, col = idx % 192;
        float v;
        if      (col < 64)  v = ncomb[g * 64 + col];
        else if (col < 128) v = ecomb[g * 64 + col - 64];
        else                v = gr[g * 64 + col - 128];
        X[idx] = v;
    }
    __syncthreads();
    {
        const int j = t & 127, gb = t >> 7;
        float a[8];
#pragma unroll
        for (int gi = 0; gi < 8; ++gi) a[gi] = b1[j];
        for (int k = 0; k < 192; ++k) {
            const float wv = W1[k * 128 + j];
#pragma unroll
            for (int gi = 0; gi < 8; ++gi) a[gi] += X[(gb + gi * 2) * 192 + k] * wv;
        }
#pragma unroll
        for (int gi = 0; gi < 8; ++gi) Hs[(gb + gi * 2) * 128 + j] = fmaxf(a[gi], 0.f);
    }
    __syncthreads();
    {
        const int j = t & 127, gb = t >> 7;
        float a[8];
#pragma unroll
        for (int gi = 0; gi < 8; ++gi) a[gi] = b2[j];
        for (int k = 0; k < 128; ++k) {
            const float wv = W2[k * 128 + j];
#pragma unroll
            for (int gi = 0; gi < 8; ++gi) a[gi] += Hs[(gb + gi * 2) * 128 + k] * wv;
        }
#pragma unroll
        for (int gi = 0; gi < 8; ++gi) H2s[(gb + gi * 2) * 128 + j] = fmaxf(a[gi], 0.f);
    }
    __syncthreads();
    {
        const int j = t & 63, gb = t >> 6;
        float a[4];
#pragma unroll
        for (int gi = 0; gi < 4; ++gi) a[gi] = b3[j];
        for (int k = 0; k < 128; ++k) {
            const float wv = W3[k * 64 + j];
#pragma unroll
            for (int gi = 0; gi < 4; ++gi) a[gi] += H2s[(gb + gi * 4) * 128 + k] * wv;
        }
#pragma unroll
        for (int gi = 0; gi < 4; ++gi) uout[(gb + gi * 4) * 64 + j] = a[gi];
    }
}

// ---------------------------------------------------------------------------
extern "C" void kernel_launch(void* const* d_in, const int* in_sizes, int n_in,
                              void* d_out, int out_size, void* d_ws, size_t ws_size,
                              hipStream_t stream)
{
    const float* edge_feat = (const float*)d_in[0];
    const float* node_feat = (const float*)d_in[1];
    const float* g_repr    = (const float*)d_in[2];
    const int*   src       = (const int*)d_in[3];
    const int*   dst       = (const int*)d_in[4];
    const int*   e2g       = (const int*)d_in[5];
    const int*   n2g       = (const int*)d_in[6];
    const float* We1 = (const float*)d_in[7];  const float* be1 = (const float*)d_in[8];
    const float* We2 = (const float*)d_in[9];  const float* be2 = (const float*)d_in[10];
    const float* We3 = (const float*)d_in[11]; const float* be3 = (const float*)d_in[12];
    const float* Wn1 = (const float*)d_in[13]; const float* bn1 = (const float*)d_in[14];
    const float* Wn2 = (const float*)d_in[15]; const float* bn2 = (const float*)d_in[16];
    const float* Wn3 = (const float*)d_in[17]; const float* bn3 = (const float*)d_in[18];
    const float* Wu1 = (const float*)d_in[19]; const float* bu1 = (const float*)d_in[20];
    const float* Wu2 = (const float*)d_in[21]; const float* bu2 = (const float*)d_in[22];
    const float* Wu3 = (const float*)d_in[23]; const float* bu3 = (const float*)d_in[24];

    const int E = in_sizes[3];   // 400000
    const int N = in_sizes[6];   // 50000

    float* e_out = (float*)d_out;
    float* n_out = e_out + (size_t)E * 64;
    float* u_out = n_out + (size_t)N * 64;

    char* wsc = (char*)d_ws;
    float* ecomb_rep = (float*)wsc;
    float* ncomb_rep = (float*)(wsc + 262144);
    float* ecomb     = (float*)(wsc + 524288);
    float* ncomb     = ecomb + 1024;
    char*  wf        = wsc + 532480;
    const char* WEsrc = wf;              // We1|We2|We3 (112 KB contiguous)
    const char* WNsrc = wf + 114688;     // Wn1|Wn2|Wn3 (96 KB contiguous)
    int* deg    = (int*)(wsc + 745472);
    int* startA = (int*)(wsc + 945472);
    int* cursor = (int*)(wsc + 1145472);
    int* psum   = (int*)(wsc + 1345472);
    int* elist  = (int*)(wsc + 1346496);
    const size_t WS_NEED = 1346496 + (size_t)E * 4;
    const bool csr = (ws_size >= WS_NEED);

    constexpr int SH_E = (112 + 48) * 1024;   // 163840 = full 160 KB
    constexpr int SH_N = (96 + 48) * 1024;    // 147456

    hipMemsetAsync(wsc, 0, 524288, stream);
    prep_weights<<<52, 256, 0, stream>>>(We1, We2, We3, Wn1, Wn2, Wn3, wf);

    const int etiles = (E + 191) / 192;
    const int ntiles = (N + 191) / 192;

    if (csr) {
        hipMemsetAsync(deg, 0, (size_t)N * 4, stream);
        const int EB = (E + 255) / 256;
        const int NB = (N + 255) / 256;
        hist_kernel <<<EB, 256, 0, stream>>>(dst, deg, E);
        scanA_kernel<<<NB, 256, 0, stream>>>(deg, psum, N);
        scanB_kernel<<<1, 256, 0, stream>>>(psum, NB);
        scanC_kernel<<<NB, 256, 0, stream>>>(deg, psum, startA, cursor, N);
        fill_kernel <<<EB, 256, 0, stream>>>(dst, cursor, elist, E);

        auto ek = mlp_fused_kernel<4, true, false, false>;
        auto nk = mlp_fused_kernel<3, false, false, true>;
        hipFuncSetAttribute((const void*)ek,
                            hipFuncAttributeMaxDynamicSharedMemorySize, SH_E);
        hipFuncSetAttribute((const void*)nk,
                            hipFuncAttributeMaxDynamicSharedMemorySize, SH_N);

        ek<<<256, 768, SH_E, stream>>>(
            edge_feat, node_feat, g_repr, src, dst, e2g,
            nullptr, nullptr, nullptr, nullptr,
            WEsrc, be1, be2, be3, e_out, nullptr, ecomb_rep, E, etiles);
        nk<<<256, 768, SH_N, stream>>>(
            node_feat, nullptr, g_repr, nullptr, nullptr, n2g,
            startA, cursor, elist, e_out,
            WNsrc, bn1, bn2, bn3, n_out, nullptr, ncomb_rep, N, ntiles);
    } else {
        hipMemsetAsync(n_out, 0, (size_t)N * 64 * sizeof(float), stream);
        auto ek = mlp_fused_kernel<4, true, true, false>;
        auto nk = mlp_fused_kernel<3, false, false, false>;
        hipFuncSetAttribute((const void*)ek,
                            hipFuncAttributeMaxDynamicSharedMemorySize, SH_E);
        hipFuncSetAttribute((const void*)nk,
                            hipFuncAttributeMaxDynamicSharedMemorySize, SH_N);
        ek<<<256, 768, SH_E, stream>>>(
            edge_feat, node_feat, g_repr, src, dst, e2g,
            nullptr, nullptr, nullptr, nullptr,
            WEsrc, be1, be2, be3, e_out, n_out, ecomb_rep, E, etiles);
        nk<<<256, 768, SH_N, stream>>>(
            node_feat, n_out, g_repr, nullptr, nullptr, n2g,
            nullptr, nullptr, nullptr, nullptr,
            WNsrc, bn1, bn2, bn3, n_out, nullptr, ncomb_rep, N, ntiles);
    }

    reduce_rep_kernel<<<8, 256, 0, stream>>>(ecomb_rep, ecomb);
    u_kernel<<<1, 256, 0, stream>>>(ncomb, ecomb, g_repr,
                                    Wu1, bu1, Wu2, bu2, Wu3, bu3, u_out);
}

// Round 11
// 303.702 us; speedup vs baseline: 1.5025x; 1.0909x over previous
//
#include <hip/hip_runtime.h>
#include <cstdint>

// GraphNets v11 = v8 base (8 waves, all weights in LDS) + per-wave independent
// chunk striding + 2-deep software pipeline (idx +2, raw-data +1, ping-pong)
// + shfl-based one-hot + hoisted biases + register comb flush.
// mfma_f32_16x16x32_bf16: A lane l: row=l&15, k=(l>>4)*8+j ; B: col=l&15, same k
// C/D: col=lane&15, row=(lane>>4)*4+reg   [verified v2-v10]

typedef short short8 __attribute__((ext_vector_type(8)));
typedef float f32x4 __attribute__((ext_vector_type(4)));

#define MFMA16(a, b, c) __builtin_amdgcn_mfma_f32_16x16x32_bf16(a, b, c, 0, 0, 0)

__device__ __forceinline__ short f2bf(float x) {
    union { __bf16 b; short s; } u; u.b = (__bf16)x; return u.s;
}
__device__ __forceinline__ short8 pack8(float4 lo, float4 hi) {
    short8 r;
    r[0] = f2bf(lo.x); r[1] = f2bf(lo.y); r[2] = f2bf(lo.z); r[3] = f2bf(lo.w);
    r[4] = f2bf(hi.x); r[5] = f2bf(hi.y); r[6] = f2bf(hi.z); r[7] = f2bf(hi.w);
    return r;
}
__device__ __forceinline__ short8 pack8v(f32x4 lo, f32x4 hi) {
    short8 r;
    r[0] = f2bf(lo[0]); r[1] = f2bf(lo[1]); r[2] = f2bf(lo[2]); r[3] = f2bf(lo[3]);
    r[4] = f2bf(hi[0]); r[5] = f2bf(hi[1]); r[6] = f2bf(hi[2]); r[7] = f2bf(hi[3]);
    return r;
}

// ---------------------------------------------------------------------------
// Weight prep (verified v2-v10). edge = We1|We2|We3 contiguous 112KB at 0,
// node = Wn1|Wn2|Wn3 contiguous 96KB at 114688.
// ---------------------------------------------------------------------------
__global__ __launch_bounds__(256)
void prep_weights(const float* __restrict__ We1, const float* __restrict__ We2,
                  const float* __restrict__ We3, const float* __restrict__ Wn1,
                  const float* __restrict__ Wn2, const float* __restrict__ Wn3,
                  char* __restrict__ out)
{
    const int fg = blockIdx.x * 4 + (threadIdx.x >> 6);
    if (fg >= 208) return;
    const int lane = threadIdx.x & 63;
    const float* W; int Ncols, f; size_t obase;
    if      (fg < 64)  { W = We1; Ncols = 128; f = fg;       obase = 0;      }
    else if (fg < 96)  { W = We2; Ncols = 128; f = fg - 64;  obase = 65536;  }
    else if (fg < 112) { W = We3; Ncols = 64;  f = fg - 96;  obase = 98304;  }
    else if (fg < 160) { W = Wn1; Ncols = 128; f = fg - 112; obase = 114688; }
    else if (fg < 192) { W = Wn2; Ncols = 128; f = fg - 160; obase = 163840; }
    else               { W = Wn3; Ncols = 64;  f = fg - 192; obase = 196608; }
    const int NF = Ncols >> 4;
    const int kf = f / NF, nf = f - kf * NF;
    const int k0 = kf * 32 + (lane >> 4) * 8;
    const int col = nf * 16 + (lane & 15);
    union { short s[8]; uint4 u; } pk;
#pragma unroll
    for (int j = 0; j < 8; ++j) pk.s[j] = f2bf(W[(size_t)(k0 + j) * Ncols + col]);
    *(uint4*)(out + obase + ((size_t)f * 64 + lane) * 16) = pk.u;
}

// ---------------------------------------------------------------------------
// CSR build (verified v4)
// ---------------------------------------------------------------------------
__global__ __launch_bounds__(256)
void hist_kernel(const int* __restrict__ dst, int* __restrict__ deg, int E)
{
    const int i = blockIdx.x * 256 + threadIdx.x;
    if (i < E) atomicAdd(&deg[dst[i]], 1);
}
__global__ __launch_bounds__(256)
void scanA_kernel(const int* __restrict__ deg, int* __restrict__ psum, int n)
{
    __shared__ int red[256];
    const int t = threadIdx.x;
    const int i = blockIdx.x * 256 + t;
    red[t] = (i < n) ? deg[i] : 0;
    __syncthreads();
    for (int s = 128; s > 0; s >>= 1) {
        if (t < s) red[t] += red[t + s];
        __syncthreads();
    }
    if (t == 0) psum[blockIdx.x] = red[0];
}
__global__ __launch_bounds__(256)
void scanB_kernel(int* __restrict__ psum, int nb)
{
    __shared__ int s[256];
    const int t = threadIdx.x;
    const int v0 = (t < nb) ? psum[t] : 0;
    s[t] = v0;
    __syncthreads();
    for (int d = 1; d < 256; d <<= 1) {
        const int v = (t >= d) ? s[t - d] : 0;
        __syncthreads();
        s[t] += v;
        __syncthreads();
    }
    if (t < nb) psum[t] = s[t] - v0;
}
__global__ __launch_bounds__(256)
void scanC_kernel(const int* __restrict__ deg, const int* __restrict__ psum,
                  int* __restrict__ start, int* __restrict__ cursor, int n)
{
    __shared__ int s[256];
    const int t = threadIdx.x;
    const int i = blockIdx.x * 256 + t;
    const int v0 = (i < n) ? deg[i] : 0;
    s[t] = v0;
    __syncthreads();
    for (int d = 1; d < 256; d <<= 1) {
        const int v = (t >= d) ? s[t - d] : 0;
        __syncthreads();
        s[t] += v;
        __syncthreads();
    }
    const int ex = s[t] - v0 + psum[blockIdx.x];
    if (i < n) { start[i] = ex; cursor[i] = ex; }
}
__global__ __launch_bounds__(256)
void fill_kernel(const int* __restrict__ dst, int* __restrict__ cursor,
                 int* __restrict__ elist, int E)
{
    const int i = blockIdx.x * 256 + threadIdx.x;
    if (i < E) {
        const int d = dst[i];
        const int p = atomicAdd(&cursor[d], 1);
        elist[p] = i;
    }
}

// ---------------------------------------------------------------------------
// Pipelined fused MLP: 512 thr = 8 waves, 1 block/CU. Each WAVE independently
// grid-strides 16-row chunks (de-phased). 2-deep pipeline: indices prefetched
// 2 chunks ahead, raw gather data 1 chunk ahead (ping-pong registers).
// ---------------------------------------------------------------------------
template <int NQ, bool IS_EDGE, bool MSG_ATOMIC, bool GATHER>
__global__ __launch_bounds__(512, 2)
void mlp_pipe_kernel(const float* __restrict__ feat0,
                     const float* feat1,
                     const float* __restrict__ gr,
                     const int* __restrict__ srcIdx, const int* __restrict__ dstIdx,
                     const int* __restrict__ seg,
                     const int* __restrict__ gstart, const int* __restrict__ gend,
                     const int* __restrict__ elist,  const float* __restrict__ gsrc,
                     const char* __restrict__ Wsrc,
                     const float* __restrict__ b1, const float* __restrict__ b2,
                     const float* __restrict__ b3,
                     float* out, float* msgs_out, float* comb_rep,
                     int M)
{
    constexpr int KF1   = NQ * 2;                  // layer-1 kf count
    constexpr int NFRAG = KF1 * 8 + 32 + 16;       // W1 + W2 + W3 frags (LDS)
    constexpr int HOFF  = NFRAG * 1024;
    constexpr int NW    = 8;                       // waves per block
    extern __shared__ char lds[];

    const int t    = threadIdx.x;
    const int lane = t & 63;
    const int w    = t >> 6;
    const int l15  = lane & 15;
    const int l4   = lane >> 4;
    char* Hs = lds + HOFF + w * 4096;              // wave-private 4KB (h1/h2/P)

    // ---- stage all weight fragments to LDS once ----
    for (int f = t; f < NFRAG * 64; f += 512)
        *(uint4*)(lds + (size_t)f * 16) = *(const uint4*)(Wsrc + (size_t)f * 16);
    __syncthreads();

    const char* W1l = lds;
    const char* W2l = lds + (size_t)KF1 * 8 * 1024;
    const char* W3l = W2l + 32 * 1024;

    // ---- hoisted biases ----
    float bv1[8], bv2[8], bv3[4];
#pragma unroll
    for (int nf = 0; nf < 8; ++nf) { bv1[nf] = b1[nf * 16 + l15]; bv2[nf] = b2[nf * 16 + l15]; }
#pragma unroll
    for (int nf = 0; nf < 4; ++nf) bv3[nf] = b3[nf * 16 + l15];

    // per-wave comb accumulators: acc_comb[nf][q] -> graph g=l4*4+q, col nf*16+l15
    f32x4 acc_comb[4];
#pragma unroll
    for (int nf = 0; nf < 4; ++nf) acc_comb[nf] = f32x4{0.f, 0.f, 0.f, 0.f};

    struct IdxT { int isrc, idst, ig, gs, ge; bool valid; };

    auto load_idx = [&](int base, IdxT& I) {
        const int row_ = base + l15;
        I.valid = row_ < M;
        I.isrc = 0; I.idst = 0; I.ig = 0; I.gs = 0; I.ge = 0;
        if (I.valid) {
            if (IS_EDGE) { I.isrc = srcIdx[row_]; I.idst = dstIdx[row_]; I.ig = seg[row_]; }
            else if (GATHER) { I.ig = seg[row_]; I.gs = gstart[row_]; I.ge = gend[row_]; }
            else { I.ig = seg[row_]; }
        }
    };

    auto load_raw = [&](int base, const IdxT& I, float4 (&raw)[KF1][2]) {
        const int row_ = base + l15;
#pragma unroll
        for (int kf = 0; kf < KF1; ++kf) {
            const int c = kf >> 1;
            if (GATHER && c == 1) continue;        // msgs computed at pack time
            float4 lo = make_float4(0.f, 0.f, 0.f, 0.f), hi = lo;
            if (I.valid) {
                const float* p;
                if (IS_EDGE) {
                    p = (c == 0) ? feat0 + (size_t)row_  * 64
                      : (c == 1) ? feat1 + (size_t)I.isrc * 64
                      : (c == 2) ? feat1 + (size_t)I.idst * 64
                      :            gr    + (size_t)I.ig   * 64;
                } else if (GATHER) {
                    p = (c == 0) ? feat0 + (size_t)row_ * 64
                      :            gr    + (size_t)I.ig * 64;
                } else {
                    p = (c == 0) ? feat0 + (size_t)row_ * 64
                      : (c == 1) ? feat1 + (size_t)row_ * 64
                      :            gr    + (size_t)I.ig * 64;
                }
                const int koff = (kf & 1) * 32 + l4 * 8;
                lo = *(const float4*)(p + koff);
                hi = *(const float4*)(p + koff + 4);
            }
            raw[kf][0] = lo; raw[kf][1] = hi;
        }
    };

    const int bstride = gridDim.x * NW * 16;

    auto tile_step = [&](int base, float4 (&rawC)[KF1][2], IdxT& IC,
                         float4 (&rawN)[KF1][2], IdxT& IN) {
        // ---- issue next chunk's raw loads first (fire-and-forget) ----
        load_raw(base + bstride, IN, rawN);

        // ---- pack current chunk into A-fragments ----
        short8 xf[KF1];
#pragma unroll
        for (int kf = 0; kf < KF1; ++kf) {
            if (GATHER && (kf >> 1) == 1) continue;
            xf[kf] = pack8(rawC[kf][0], rawC[kf][1]);
        }
        if constexpr (GATHER) {
            f32x4 m0 = {0,0,0,0}, m1 = m0, m2 = m0, m3 = m0;
            if (IC.valid) {
                for (int j = IC.gs; j < IC.ge; ++j) {
                    const float* er = gsrc + (size_t)elist[j] * 64 + l4 * 8;
                    m0 += *(const f32x4*)(er);
                    m1 += *(const f32x4*)(er + 4);
                    m2 += *(const f32x4*)(er + 32);
                    m3 += *(const f32x4*)(er + 36);
                }
            }
            xf[2] = pack8v(m0, m1);
            xf[3] = pack8v(m2, m3);
        }
        const int igc = IC.ig;          // this lane's seg for row base+l15

        // ---- prefetch indices 2 chunks ahead into IC's slot ----
        load_idx(base + 2 * bstride, IC);

        // ---- layer 1 ----
        f32x4 acc[8];
#pragma unroll
        for (int nf = 0; nf < 8; ++nf) acc[nf] = f32x4{bv1[nf], bv1[nf], bv1[nf], bv1[nf]};
#pragma unroll
        for (int kf = 0; kf < KF1; ++kf) {
#pragma unroll
            for (int nf = 0; nf < 8; ++nf) {
                short8 bw = *(const short8*)(W1l + ((size_t)(kf * 8 + nf) * 64 + lane) * 16);
                acc[nf] = MFMA16(xf[kf], bw, acc[nf]);
            }
        }
#pragma unroll
        for (int nf = 0; nf < 8; ++nf)
#pragma unroll
            for (int q = 0; q < 4; ++q) {
                const int rowL = l4 * 4 + q;
                const int slot = (nf * 2 + (l15 >> 3)) ^ (rowL & 7);
                *(short*)(Hs + rowL * 256 + slot * 16 + (l15 & 7) * 2) =
                    f2bf(fmaxf(acc[nf][q], 0.f));
            }

        // ---- layer 2 ----
        f32x4 acc2[8];
#pragma unroll
        for (int nf = 0; nf < 8; ++nf) acc2[nf] = f32x4{bv2[nf], bv2[nf], bv2[nf], bv2[nf]};
#pragma unroll
        for (int kf = 0; kf < 4; ++kf) {
            const int slot = (kf * 4 + l4) ^ (l15 & 7);
            short8 a = *(short8*)(Hs + l15 * 256 + slot * 16);
#pragma unroll
            for (int nf = 0; nf < 8; ++nf) {
                short8 bw = *(const short8*)(W2l + ((size_t)(kf * 8 + nf) * 64 + lane) * 16);
                acc2[nf] = MFMA16(a, bw, acc2[nf]);
            }
        }
#pragma unroll
        for (int nf = 0; nf < 8; ++nf)
#pragma unroll
            for (int q = 0; q < 4; ++q) {
                const int rowL = l4 * 4 + q;
                const int slot = (nf * 2 + (l15 >> 3)) ^ (rowL & 7);
                *(short*)(Hs + rowL * 256 + slot * 16 + (l15 & 7) * 2) =
                    f2bf(fmaxf(acc2[nf][q], 0.f));
            }

        // ---- layer 3 ----
        f32x4 acc3[4];
#pragma unroll
        for (int nf = 0; nf < 4; ++nf) acc3[nf] = f32x4{bv3[nf], bv3[nf], bv3[nf], bv3[nf]};
#pragma unroll
        for (int kf = 0; kf < 4; ++kf) {
            const int slot = (kf * 4 + l4) ^ (l15 & 7);
            short8 a = *(short8*)(Hs + l15 * 256 + slot * 16);
#pragma unroll
            for (int nf = 0; nf < 4; ++nf) {
                short8 bw = *(const short8*)(W3l + ((size_t)(kf * 4 + nf) * 64 + lane) * 16);
                acc3[nf] = MFMA16(a, bw, acc3[nf]);
            }
        }

        // ---- comb via one-hot MFMA; P staged with slot-XOR (v10-verified) ----
#pragma unroll
        for (int nf = 0; nf < 4; ++nf) {
            union { unsigned u; short s[2]; } p01, p23;
            p01.s[0] = f2bf(acc3[nf][0]); p01.s[1] = f2bf(acc3[nf][1]);
            p23.s[0] = f2bf(acc3[nf][2]); p23.s[1] = f2bf(acc3[nf][3]);
            const int col = nf * 16 + l15;
            const int sw  = ((l4 >> 1) ^ (col & 3));
            char* pc = Hs + col * 64 + sw * 16 + (l4 & 1) * 8;
            *(unsigned*)(pc)     = p01.u;
            *(unsigned*)(pc + 4) = p23.u;
        }
        short8 oh;
#pragma unroll
        for (int j = 0; j < 8; ++j) {
            const int sg = __shfl(igc, l4 * 8 + j);   // seg[base + l4*8 + j]
            short v = 0;
            if (l4 < 2) {
                const int rr = base + l4 * 8 + j;
                if (rr < M && sg == l15) v = (short)0x3F80;  // bf16 1.0
            }
            oh[j] = v;
        }
#pragma unroll
        for (int nf = 0; nf < 4; ++nf) {
            const int col = nf * 16 + l15;
            const int sr  = l4 ^ (col & 3);
            short8 bp = *(short8*)(Hs + col * 64 + sr * 16);
            acc_comb[nf] = MFMA16(oh, bp, acc_comb[nf]);
        }

        // ---- epilogue: store out (+ fallback msgs atomics) ----
#pragma unroll
        for (int q = 0; q < 4; ++q) {
            const int grow = base + l4 * 4 + q;
            if (grow < M) {
                int d = 0;
                if (MSG_ATOMIC) d = dstIdx[grow];
#pragma unroll
                for (int nf = 0; nf < 4; ++nf) {
                    const int col = nf * 16 + l15;
                    const float v = acc3[nf][q];
                    out[(size_t)grow * 64 + col] = v;
                    if constexpr (MSG_ATOMIC)
                        atomicAdd(msgs_out + (size_t)d * 64 + col, v);
                }
            }
        }
    };

    // ---- per-wave pipelined loop (ping-pong raw buffers) ----
    {
        int base = (blockIdx.x * NW + w) * 16;
        IdxT IA, IB;
        float4 rawA[KF1][2], rawB[KF1][2];
        load_idx(base, IA);
        load_raw(base, IA, rawA);
        load_idx(base + bstride, IB);
        while (true) {
            tile_step(base, rawA, IA, rawB, IB);
            base += bstride;
            if (base >= M) break;
            tile_step(base, rawB, IB, rawA, IA);
            base += bstride;
            if (base >= M) break;
        }
    }

    // ---- flush: acc_comb -> own Hs slice -> cross-wave tree reduce ----
#pragma unroll
    for (int nf = 0; nf < 4; ++nf)
#pragma unroll
        for (int q = 0; q < 4; ++q)
            ((float*)Hs)[(l4 * 4 + q) * 64 + nf * 16 + l15] = acc_comb[nf][q];
    __syncthreads();
    float* hbase = (float*)(lds + HOFF);
    float* rep = comb_rep + (size_t)(blockIdx.x & 63) * 1024;
    for (int i = t; i < 1024; i += 512) {
        float s = 0.f;
#pragma unroll
        for (int wv = 0; wv < NW; ++wv) s += hbase[wv * 1024 + i];
        atomicAdd(rep + i, s);
    }
}

// ---------------------------------------------------------------------------
__global__ __launch_bounds__(256)
void reduce_rep_kernel(const float* __restrict__ rep, float* __restrict__ outv)
{
    const int s = blockIdx.x * 256 + threadIdx.x;   // 0..2047
    const int arr = s >> 10, idx = s & 1023;
    const float* p = rep + (size_t)arr * 65536 + idx;
    float v = 0.f;
#pragma unroll 8
    for (int r = 0; r < 64; ++r) v += p[(size_t)r * 1024];
    outv[s] = v;
}

// ---------------------------------------------------------------------------
__global__ __launch_bounds__(256)
void u_kernel(const float* __restrict__ ncomb, const float* __restrict__ ecomb,
              const float* __restrict__ gr,
              const float* __restrict__ W1, const float* __restrict__ b1,
              const float* __restrict__ W2, const float* __restrict__ b2,
              const float* __restrict__ W3, const float* __restrict__ b3,
              float* uout)
{
    __shared__ float X[16 * 192];
    __shared__ float Hs[16 * 128];
    __shared__ float H2s[16 * 128];
    const int t = threadIdx.x;
#pragma unroll
    for (int i = 0; i < 12; ++i) {
        const int idx = i * 256 + t;
        const int g = idx / 192, col = idx % 192;
        float v;
        if      (col < 64)  v = ncomb[g * 64 + col];
        else if (col < 128) v = ecomb[g * 64 + col - 64];
        else                v = gr[g * 64 + col - 128];
        X[idx] = v;
    }
    __syncthreads();
    {
        const int j = t & 127, gb = t >> 7;
        float a[8];
#pragma unroll
        for (int gi = 0; gi < 8; ++gi) a[gi] = b1[j];
        for (int k = 0; k < 192; ++k) {
            const float wv = W1[k * 128 + j];
#pragma unroll
            for (int gi = 0; gi < 8; ++gi) a[gi] += X[(gb + gi * 2) * 192 + k] * wv;
        }
#pragma unroll
        for (int gi = 0; gi < 8; ++gi) Hs[(gb + gi * 2) * 128 + j] = fmaxf(a[gi], 0.f);
    }
    __syncthreads();
    {
        const int j = t & 127, gb = t >> 7;
        float a[8];
#pragma unroll
        for (int gi = 0; gi < 8; ++gi) a[gi] = b2[j];
        for (int k = 0; k < 128; ++k) {
            const float wv = W2[k * 128 + j];
#pragma unroll
            for (int gi = 0; gi < 8; ++gi) a[gi] += Hs[(gb + gi * 2) * 128 + k] * wv;
        }
#pragma unroll
        for (int gi = 0; gi < 8; ++gi) H2s[(gb + gi * 2) * 128 + j] = fmaxf(a[gi], 0.f);
    }
    __syncthreads();
    {
        const int j = t & 63, gb = t >> 6;
        float a[4];
#pragma unroll
        for (int gi = 0; gi < 4; ++gi) a[gi] = b3[j];
        for (int k = 0; k < 128; ++k) {
            const float wv = W3[k * 64 + j];
#pragma unroll
            for (int gi = 0; gi < 4; ++gi) a[gi] += H2s[(gb + gi * 4) * 128 + k] * wv;
        }
#pragma unroll
        for (int gi = 0; gi < 4; ++gi) uout[(gb + gi * 4) * 64 + j] = a[gi];
    }
}

// ---------------------------------------------------------------------------
extern "C" void kernel_launch(void* const* d_in, const int* in_sizes, int n_in,
                              void* d_out, int out_size, void* d_ws, size_t ws_size,
                              hipStream_t stream)
{
    const float* edge_feat = (const float*)d_in[0];
    const float* node_feat = (const float*)d_in[1];
    const float* g_repr    = (const float*)d_in[2];
    const int*   src       = (const int*)d_in[3];
    const int*   dst       = (const int*)d_in[4];
    const int*   e2g       = (const int*)d_in[5];
    const int*   n2g       = (const int*)d_in[6];
    const float* We1 = (const float*)d_in[7];  const float* be1 = (const float*)d_in[8];
    const float* We2 = (const float*)d_in[9];  const float* be2 = (const float*)d_in[10];
    const float* We3 = (const float*)d_in[11]; const float* be3 = (const float*)d_in[12];
    const float* Wn1 = (const float*)d_in[13]; const float* bn1 = (const float*)d_in[14];
    const float* Wn2 = (const float*)d_in[15]; const float* bn2 = (const float*)d_in[16];
    const float* Wn3 = (const float*)d_in[17]; const float* bn3 = (const float*)d_in[18];
    const float* Wu1 = (const float*)d_in[19]; const float* bu1 = (const float*)d_in[20];
    const float* Wu2 = (const float*)d_in[21]; const float* bu2 = (const float*)d_in[22];
    const float* Wu3 = (const float*)d_in[23]; const float* bu3 = (const float*)d_in[24];

    const int E = in_sizes[3];   // 400000
    const int N = in_sizes[6];   // 50000

    float* e_out = (float*)d_out;
    float* n_out = e_out + (size_t)E * 64;
    float* u_out = n_out + (size_t)N * 64;

    char* wsc = (char*)d_ws;
    float* ecomb_rep = (float*)wsc;
    float* ncomb_rep = (float*)(wsc + 262144);
    float* ecomb     = (float*)(wsc + 524288);
    float* ncomb     = ecomb + 1024;
    char*  wf        = wsc + 532480;
    const char* WEsrc = wf;              // We1|We2|We3 (112 KB contiguous)
    const char* WNsrc = wf + 114688;     // Wn1|Wn2|Wn3 (96 KB contiguous)
    int* deg    = (int*)(wsc + 745472);
    int* startA = (int*)(wsc + 945472);
    int* cursor = (int*)(wsc + 1145472);
    int* psum   = (int*)(wsc + 1345472);
    int* elist  = (int*)(wsc + 1346496);
    const size_t WS_NEED = 1346496 + (size_t)E * 4;
    const bool csr = (ws_size >= WS_NEED);

    constexpr int SH_E = (112 + 32) * 1024;   // 147456
    constexpr int SH_N = (96 + 32) * 1024;    // 131072

    hipMemsetAsync(wsc, 0, 524288, stream);
    prep_weights<<<52, 256, 0, stream>>>(We1, We2, We3, Wn1, Wn2, Wn3, wf);

    if (csr) {
        hipMemsetAsync(deg, 0, (size_t)N * 4, stream);
        const int EB = (E + 255) / 256;
        const int NB = (N + 255) / 256;
        hist_kernel <<<EB, 256, 0, stream>>>(dst, deg, E);
        scanA_kernel<<<NB, 256, 0, stream>>>(deg, psum, N);
        scanB_kernel<<<1, 256, 0, stream>>>(psum, NB);
        scanC_kernel<<<NB, 256, 0, stream>>>(deg, psum, startA, cursor, N);
        fill_kernel <<<EB, 256, 0, stream>>>(dst, cursor, elist, E);

        auto ek = mlp_pipe_kernel<4, true, false, false>;
        auto nk = mlp_pipe_kernel<3, false, false, true>;
        hipFuncSetAttribute((const void*)ek,
                            hipFuncAttributeMaxDynamicSharedMemorySize, SH_E);
        hipFuncSetAttribute((const void*)nk,
                            hipFuncAttributeMaxDynamicSharedMemorySize, SH_N);

        ek<<<256, 512, SH_E, stream>>>(
            edge_feat, node_feat, g_repr, src, dst, e2g,
            nullptr, nullptr, nullptr, nullptr,
            WEsrc, be1, be2, be3, e_out, nullptr, ecomb_rep, E);
        nk<<<256, 512, SH_N, stream>>>(
            node_feat, nullptr, g_repr, nullptr, nullptr, n2g,
            startA, cursor, elist, e_out,
            WNsrc, bn1, bn2, bn3, n_out, nullptr, ncomb_rep, N);
    } else {
        hipMemsetAsync(n_out, 0, (size_t)N * 64 * sizeof(float), stream);
        auto ek = mlp_pipe_kernel<4, true, true, false>;
        auto nk = mlp_pipe_kernel<3, false, false, false>;
        hipFuncSetAttribute((const void*)ek,
                            hipFuncAttributeMaxDynamicSharedMemorySize, SH_E);
        hipFuncSetAttribute((const void*)nk,
                            hipFuncAttributeMaxDynamicSharedMemorySize, SH_N);
        ek<<<256, 512, SH_E, stream>>>(
            edge_feat, node_feat, g_repr, src, dst, e2g,
            nullptr, nullptr, nullptr, nullptr,
            WEsrc, be1, be2, be3, e_out, n_out, ecomb_rep, E);
        nk<<<256, 512, SH_N, stream>>>(
            node_feat, n_out, g_repr, nullptr, nullptr, n2g,
            nullptr, nullptr, nullptr, nullptr,
            WNsrc, bn1, bn2, bn3, n_out, nullptr, ncomb_rep, N);
    }

    reduce_rep_kernel<<<8, 256, 0, stream>>>(ecomb_rep, ecomb);
    u_kernel<<<1, 256, 0, stream>>>(ncomb, ecomb, g_repr,
                                    Wu1, bu1, Wu2, bu2, Wu3, bu3, u_out);
}

// Round 12
// 248.902 us; speedup vs baseline: 1.8333x; 1.2202x over previous
//
#include <hip/hip_runtime.h>
#include <cstdint>

// GraphNets v12: 32 rows/wave, swapped-operand layers 1-2 (h^T output, packed
// b64 h-writes), g_repr folded into per-graph G table (K 256->192 / 192->128),
// G applied via one-hot MFMA from register-resident fragments. Layer 3 + comb
// + epilogue keep the v8-verified standard layout. 8 waves, weights in LDS.
// mfma_f32_16x16x32_bf16: A lane l: row=l&15, k=(l>>4)*8+j ; B: col=l&15, same k
// C/D: col=lane&15, row=(lane>>4)*4+reg   [verified v2-v11]

typedef short short8 __attribute__((ext_vector_type(8)));
typedef float f32x4 __attribute__((ext_vector_type(4)));

#define MFMA16(a, b, c) __builtin_amdgcn_mfma_f32_16x16x32_bf16(a, b, c, 0, 0, 0)

__device__ __forceinline__ short f2bf(float x) {
    union { __bf16 b; short s; } u; u.b = (__bf16)x; return u.s;
}
__device__ __forceinline__ unsigned pkbf(float a, float b) {
    return (unsigned)(unsigned short)f2bf(a) |
           ((unsigned)(unsigned short)f2bf(b) << 16);
}
__device__ __forceinline__ short8 pack8(float4 lo, float4 hi) {
    short8 r;
    r[0] = f2bf(lo.x); r[1] = f2bf(lo.y); r[2] = f2bf(lo.z); r[3] = f2bf(lo.w);
    r[4] = f2bf(hi.x); r[5] = f2bf(hi.y); r[6] = f2bf(hi.z); r[7] = f2bf(hi.w);
    return r;
}
__device__ __forceinline__ short8 pack8v(f32x4 lo, f32x4 hi) {
    short8 r;
    r[0] = f2bf(lo[0]); r[1] = f2bf(lo[1]); r[2] = f2bf(lo[2]); r[3] = f2bf(lo[3]);
    r[4] = f2bf(hi[0]); r[5] = f2bf(hi[1]); r[6] = f2bf(hi[2]); r[7] = f2bf(hi[3]);
    return r;
}

// ---------------------------------------------------------------------------
// Weight prep: frag format verified v2-v11 (1024B frags, lane-contiguous;
// identical lane map serves as A- or B-operand). New regions (rel to wf):
//   edge: W1'[K=192] 48K @0 | We2 32K @49152 | We3 16K @81920   (96 KB)
//   node: Wn1'[K=128] 32K @98304 | Wn2 32K @131072 | Wn3 16K @163840 (80 KB)
// ---------------------------------------------------------------------------
__global__ __launch_bounds__(256)
void prep_weights(const float* __restrict__ We1, const float* __restrict__ We2,
                  const float* __restrict__ We3, const float* __restrict__ Wn1,
                  const float* __restrict__ Wn2, const float* __restrict__ Wn3,
                  char* __restrict__ out)
{
    const int fg = blockIdx.x * 4 + (threadIdx.x >> 6);
    if (fg >= 176) return;
    const int lane = threadIdx.x & 63;
    const float* W; int Ncols, f; size_t obase;
    if      (fg < 48)  { W = We1; Ncols = 128; f = fg;       obase = 0;      }
    else if (fg < 80)  { W = We2; Ncols = 128; f = fg - 48;  obase = 49152;  }
    else if (fg < 96)  { W = We3; Ncols = 64;  f = fg - 80;  obase = 81920;  }
    else if (fg < 128) { W = Wn1; Ncols = 128; f = fg - 96;  obase = 98304;  }
    else if (fg < 160) { W = Wn2; Ncols = 128; f = fg - 128; obase = 131072; }
    else               { W = Wn3; Ncols = 64;  f = fg - 160; obase = 163840; }
    const int NF = Ncols >> 4;
    const int kf = f / NF, nf = f - kf * NF;
    const int k0 = kf * 32 + (lane >> 4) * 8;
    const int col = nf * 16 + (lane & 15);
    union { short s[8]; uint4 u; } pk;
#pragma unroll
    for (int j = 0; j < 8; ++j) pk.s[j] = f2bf(W[(size_t)(k0 + j) * Ncols + col]);
    *(uint4*)(out + obase + ((size_t)f * 64 + lane) * 16) = pk.u;
}

// ---------------------------------------------------------------------------
// G prep: G[g][hcol] = bias[hcol] + sum_k g_repr[g][k] * W1tail[k][hcol],
// emitted directly as 8 A-layout frags (1KB each): elem[lane][j] =
// G[(lane>>4)*8+j][nf*16+(lane&15)], zero for k>=16. Ge @0, Gn @8192.
// ---------------------------------------------------------------------------
__global__ __launch_bounds__(256)
void prep_g(const float* __restrict__ grepr,
            const float* __restrict__ We1, const float* __restrict__ be1,
            const float* __restrict__ Wn1, const float* __restrict__ bn1,
            char* __restrict__ gout)
{
    const int gid = blockIdx.x * 256 + threadIdx.x;   // 0..1023
    if (gid >= 1024) return;
    const int table = gid >> 9, slot = gid & 511;
    const int nf = slot >> 6, lane = slot & 63;
    const int l4 = lane >> 4, l15 = lane & 15;
    const float* W   = table ? Wn1 : We1;
    const float* bia = table ? bn1 : be1;
    const int Koff   = table ? 128 : 192;
    const int hcol = nf * 16 + l15;
    union { short s[8]; uint4 u; } r;
#pragma unroll
    for (int j = 0; j < 8; ++j) {
        short v = 0;
        if (l4 < 2) {
            const int g = l4 * 8 + j;
            float s = bia[hcol];
            for (int k = 0; k < 64; ++k)
                s += grepr[g * 64 + k] * W[(size_t)(Koff + k) * 128 + hcol];
            v = f2bf(s);
        }
        r.s[j] = v;
    }
    *(uint4*)(gout + table * 8192 + ((size_t)nf * 64 + lane) * 16) = r.u;
}

// ---------------------------------------------------------------------------
// CSR build (verified v4)
// ---------------------------------------------------------------------------
__global__ __launch_bounds__(256)
void hist_kernel(const int* __restrict__ dst, int* __restrict__ deg, int E)
{
    const int i = blockIdx.x * 256 + threadIdx.x;
    if (i < E) atomicAdd(&deg[dst[i]], 1);
}
__global__ __launch_bounds__(256)
void scanA_kernel(const int* __restrict__ deg, int* __restrict__ psum, int n)
{
    __shared__ int red[256];
    const int t = threadIdx.x;
    const int i = blockIdx.x * 256 + t;
    red[t] = (i < n) ? deg[i] : 0;
    __syncthreads();
    for (int s = 128; s > 0; s >>= 1) {
        if (t < s) red[t] += red[t + s];
        __syncthreads();
    }
    if (t == 0) psum[blockIdx.x] = red[0];
}
__global__ __launch_bounds__(256)
void scanB_kernel(int* __restrict__ psum, int nb)
{
    __shared__ int s[256];
    const int t = threadIdx.x;
    const int v0 = (t < nb) ? psum[t] : 0;
    s[t] = v0;
    __syncthreads();
    for (int d = 1; d < 256; d <<= 1) {
        const int v = (t >= d) ? s[t - d] : 0;
        __syncthreads();
        s[t] += v;
        __syncthreads();
    }
    if (t < nb) psum[t] = s[t] - v0;
}
__global__ __launch_bounds__(256)
void scanC_kernel(const int* __restrict__ deg, const int* __restrict__ psum,
                  int* __restrict__ start, int* __restrict__ cursor, int n)
{
    __shared__ int s[256];
    const int t = threadIdx.x;
    const int i = blockIdx.x * 256 + t;
    const int v0 = (i < n) ? deg[i] : 0;
    s[t] = v0;
    __syncthreads();
    for (int d = 1; d < 256; d <<= 1) {
        const int v = (t >= d) ? s[t - d] : 0;
        __syncthreads();
        s[t] += v;
        __syncthreads();
    }
    const int ex = s[t] - v0 + psum[blockIdx.x];
    if (i < n) { start[i] = ex; cursor[i] = ex; }
}
__global__ __launch_bounds__(256)
void fill_kernel(const int* __restrict__ dst, int* __restrict__ cursor,
                 int* __restrict__ elist, int E)
{
    const int i = blockIdx.x * 256 + threadIdx.x;
    if (i < E) {
        const int d = dst[i];
        const int p = atomicAdd(&cursor[d], 1);
        elist[p] = i;
    }
}

// ---------------------------------------------------------------------------
// v12 fused MLP. 512 thr = 8 waves, 1 block/CU. Wave owns 32 rows (2 groups
// of 16); block tile = 256 rows, grid-stride contiguous. NQ = input chunks
// (edge 3, node 2), KF1 = NQ*2.
// LDS: [W1'|W2|W3 = (KF1*8+48) KB] + 8 waves x 8KB h-slice.
// ---------------------------------------------------------------------------
template <int NQ, bool IS_EDGE, bool MSG_ATOMIC, bool GATHER>
__global__ __launch_bounds__(512, 2)
void mlp_v12_kernel(const float* __restrict__ feat0,
                    const float* feat1,
                    const int* __restrict__ srcIdx, const int* __restrict__ dstIdx,
                    const int* __restrict__ seg,
                    const int* __restrict__ gstart, const int* __restrict__ gend,
                    const int* __restrict__ elist,  const float* __restrict__ gsrc,
                    const char* __restrict__ Wsrc,  const char* __restrict__ Gsrc,
                    const float* __restrict__ b2,   const float* __restrict__ b3,
                    float* out, float* msgs_out, float* comb_rep,
                    int M, int ntiles)
{
    constexpr int KF1   = NQ * 2;
    constexpr int NFRAG = KF1 * 8 + 32 + 16;
    constexpr int HOFF  = NFRAG * 1024;
    extern __shared__ char lds[];

    const int t    = threadIdx.x;
    const int lane = t & 63;
    const int w    = t >> 6;
    const int l15  = lane & 15;
    const int l4   = lane >> 4;
    char* Hs = lds + HOFF + w * 8192;              // wave-private 8KB

    // ---- stage weight fragments ----
    for (int f = t; f < NFRAG * 64; f += 512)
        *(uint4*)(lds + (size_t)f * 16) = *(const uint4*)(Wsrc + (size_t)f * 16);
    __syncthreads();

    const char* W1l = lds;
    const char* W2l = lds + (size_t)KF1 * 8 * 1024;
    const char* W3l = W2l + 32 * 1024;

    // ---- G fragments -> registers (8 KB table, persistent) ----
    short8 gfrag[8];
#pragma unroll
    for (int nf = 0; nf < 8; ++nf)
        gfrag[nf] = *(const short8*)(Gsrc + ((size_t)nf * 64 + lane) * 16);

    // ---- hoisted biases ----
    f32x4 bv2q[8];
#pragma unroll
    for (int nf = 0; nf < 8; ++nf)
        bv2q[nf] = *(const f32x4*)(b2 + nf * 16 + l4 * 4);
    float bv3[4];
#pragma unroll
    for (int nf = 0; nf < 4; ++nf) bv3[nf] = b3[nf * 16 + l15];

    f32x4 acc_comb[4];
#pragma unroll
    for (int nf = 0; nf < 4; ++nf) acc_comb[nf] = f32x4{0.f, 0.f, 0.f, 0.f};

    // ---- index state: [group] current + next (prefetched) ----
    int cig[2], cis[2], cid[2], cgs[2], cge[2];
    int nig[2], nis[2], nid[2], ngs[2], nge[2];
    auto load_idx = [&](int base, int (&ig)[2], int (&is)[2], int (&id)[2],
                        int (&gs)[2], int (&ge)[2]) {
#pragma unroll
        for (int g = 0; g < 2; ++g) {
            const int row = base + g * 16 + l15;
            ig[g] = 0; is[g] = 0; id[g] = 0; gs[g] = 0; ge[g] = 0;
            if (row < M) {
                ig[g] = seg[row];
                if (IS_EDGE) { is[g] = srcIdx[row]; id[g] = dstIdx[row]; }
                if (GATHER)  { gs[g] = gstart[row]; ge[g] = gend[row]; }
            }
        }
    };

    const int bstride = gridDim.x * 256;
    int base0 = blockIdx.x * 256 + w * 32;
    load_idx(base0, cig, cis, cid, cgs, cge);

    for (int base = base0; base < M + (int)(w * 32); base += bstride) {
        if (base >= M + 256) break;   // safety (never taken; loop cond governs)

        // ---- gather X into B-fragment registers ----
        short8 xf[2][KF1];
#pragma unroll
        for (int g = 0; g < 2; ++g) {
            const int row = base + g * 16 + l15;
            const bool valid = row < M;
#pragma unroll
            for (int kf = 0; kf < KF1; ++kf) {
                const int c = kf >> 1;
                if (GATHER && c == 1) continue;
                float4 lo = make_float4(0.f, 0.f, 0.f, 0.f), hi = lo;
                if (valid) {
                    const float* p;
                    if (IS_EDGE) {
                        p = (c == 0) ? feat0 + (size_t)row    * 64
                          : (c == 1) ? feat1 + (size_t)cis[g] * 64
                          :            feat1 + (size_t)cid[g] * 64;
                    } else if (GATHER) {
                        p = feat0 + (size_t)row * 64;
                    } else {
                        p = (c == 0) ? feat0 + (size_t)row * 64
                          :            feat1 + (size_t)row * 64;
                    }
                    const int koff = (kf & 1) * 32 + l4 * 8;
                    lo = *(const float4*)(p + koff);
                    hi = *(const float4*)(p + koff + 4);
                }
                xf[g][kf] = pack8(lo, hi);
            }
            if constexpr (GATHER) {
                f32x4 m0 = {0,0,0,0}, m1 = m0, m2 = m0, m3 = m0;
                if (valid) {
                    for (int j = cgs[g]; j < cge[g]; ++j) {
                        const float* er = gsrc + (size_t)elist[j] * 64 + l4 * 8;
                        m0 += *(const f32x4*)(er);
                        m1 += *(const f32x4*)(er + 4);
                        m2 += *(const f32x4*)(er + 32);
                        m3 += *(const f32x4*)(er + 36);
                    }
                }
                xf[g][2] = pack8v(m0, m1);
                xf[g][3] = pack8v(m2, m3);
            }
        }
        const int ig0 = cig[0], ig1 = cig[1];
        int idst_fb[2] = { cid[0], cid[1] };
        (void)idst_fb;

        // ---- prefetch next chunk's indices ----
        load_idx(base + bstride, nig, nis, nid, ngs, nge);

        // ---- layer 1 (swapped): accT[g][nf] = h1^T frag; init via G one-hot ----
        f32x4 accT[2][8];
#pragma unroll
        for (int g = 0; g < 2; ++g) {
            short8 ohb;
            const int igg = g ? ig1 : ig0;
#pragma unroll
            for (int j = 0; j < 8; ++j)
                ohb[j] = (l4 * 8 + j == igg) ? (short)0x3F80 : (short)0;
#pragma unroll
            for (int nf = 0; nf < 8; ++nf)
                accT[g][nf] = MFMA16(gfrag[nf], ohb, (f32x4{0.f, 0.f, 0.f, 0.f}));
        }
#pragma unroll
        for (int kf = 0; kf < KF1; ++kf) {
#pragma unroll
            for (int nf = 0; nf < 8; ++nf) {
                short8 wf = *(const short8*)(W1l + ((size_t)(kf * 8 + nf) * 64 + lane) * 16);
                accT[0][nf] = MFMA16(wf, xf[0][kf], accT[0][nf]);
                accT[1][nf] = MFMA16(wf, xf[1][kf], accT[1][nf]);
            }
        }
        // h1 write: lane owns xrow=l15 (col), hcols nf*16+l4*4+q -> packed b64
#pragma unroll
        for (int g = 0; g < 2; ++g) {
            const int row = g * 16 + l15;
#pragma unroll
            for (int nf = 0; nf < 8; ++nf) {
                uint2 hw;
                hw.x = pkbf(fmaxf(accT[g][nf][0], 0.f), fmaxf(accT[g][nf][1], 0.f));
                hw.y = pkbf(fmaxf(accT[g][nf][2], 0.f), fmaxf(accT[g][nf][3], 0.f));
                const int slot = nf * 2 + (l4 >> 1);
                const int phys = slot ^ (row & 7);
                *(uint2*)(Hs + row * 256 + phys * 16 + (l4 & 1) * 8) = hw;
            }
        }

        // ---- layer 2 (swapped): B from h1 LDS, A = W2 ----
        f32x4 accT2[2][8];
#pragma unroll
        for (int g = 0; g < 2; ++g)
#pragma unroll
            for (int nf = 0; nf < 8; ++nf) accT2[g][nf] = bv2q[nf];
#pragma unroll
        for (int kf = 0; kf < 4; ++kf) {
            short8 bf[2];
#pragma unroll
            for (int g = 0; g < 2; ++g) {
                const int row = g * 16 + l15;
                const int phys = (kf * 4 + l4) ^ (row & 7);
                bf[g] = *(short8*)(Hs + row * 256 + phys * 16);
            }
#pragma unroll
            for (int nf = 0; nf < 8; ++nf) {
                short8 wf = *(const short8*)(W2l + ((size_t)(kf * 8 + nf) * 64 + lane) * 16);
                accT2[0][nf] = MFMA16(wf, bf[0], accT2[0][nf]);
                accT2[1][nf] = MFMA16(wf, bf[1], accT2[1][nf]);
            }
        }
        // h2 write (aliases h1; in-wave DS order safe)
#pragma unroll
        for (int g = 0; g < 2; ++g) {
            const int row = g * 16 + l15;
#pragma unroll
            for (int nf = 0; nf < 8; ++nf) {
                uint2 hw;
                hw.x = pkbf(fmaxf(accT2[g][nf][0], 0.f), fmaxf(accT2[g][nf][1], 0.f));
                hw.y = pkbf(fmaxf(accT2[g][nf][2], 0.f), fmaxf(accT2[g][nf][3], 0.f));
                const int slot = nf * 2 + (l4 >> 1);
                const int phys = slot ^ (row & 7);
                *(uint2*)(Hs + row * 256 + phys * 16 + (l4 & 1) * 8) = hw;
            }
        }

        // ---- layer 3 (standard): A from h2 LDS, B = W3 ----
        f32x4 acc3[2][4];
#pragma unroll
        for (int g = 0; g < 2; ++g)
#pragma unroll
            for (int nf = 0; nf < 4; ++nf)
                acc3[g][nf] = f32x4{bv3[nf], bv3[nf], bv3[nf], bv3[nf]};
#pragma unroll
        for (int kf = 0; kf < 4; ++kf) {
            short8 af[2];
#pragma unroll
            for (int g = 0; g < 2; ++g) {
                const int row = g * 16 + l15;
                const int phys = (kf * 4 + l4) ^ (row & 7);
                af[g] = *(short8*)(Hs + row * 256 + phys * 16);
            }
#pragma unroll
            for (int nf = 0; nf < 4; ++nf) {
                short8 wf = *(const short8*)(W3l + ((size_t)(kf * 4 + nf) * 64 + lane) * 16);
                acc3[0][nf] = MFMA16(af[0], wf, acc3[0][nf]);
                acc3[1][nf] = MFMA16(af[1], wf, acc3[1][nf]);
            }
        }

        // ---- comb: P staging (full 32-row K) + one-hot MFMA ----
#pragma unroll
        for (int g = 0; g < 2; ++g)
#pragma unroll
            for (int nf = 0; nf < 4; ++nf) {
                uint2 pw;
                pw.x = pkbf(acc3[g][nf][0], acc3[g][nf][1]);
                pw.y = pkbf(acc3[g][nf][2], acc3[g][nf][3]);
                const int featcol = nf * 16 + l15;
                const int slot = g * 2 + (l4 >> 1);
                const int phys = slot ^ (l15 & 3);
                *(uint2*)(Hs + featcol * 64 + phys * 16 + (l4 & 1) * 8) = pw;
            }
        short8 oh;
#pragma unroll
        for (int j = 0; j < 8; ++j) {
            const int srcl = (l4 & 1) * 8 + j;
            const int s0 = __shfl(ig0, srcl);
            const int s1 = __shfl(ig1, srcl);
            const int sg = (l4 < 2) ? s0 : s1;
            const int rr = base + l4 * 8 + j;
            oh[j] = (rr < M && sg == l15) ? (short)0x3F80 : (short)0;
        }
#pragma unroll
        for (int nf = 0; nf < 4; ++nf) {
            const int featcol = nf * 16 + l15;
            const int phys = l4 ^ (l15 & 3);
            short8 bp = *(short8*)(Hs + featcol * 64 + phys * 16);
            acc_comb[nf] = MFMA16(oh, bp, acc_comb[nf]);
        }

        // ---- epilogue ----
#pragma unroll
        for (int g = 0; g < 2; ++g)
#pragma unroll
            for (int q = 0; q < 4; ++q) {
                const int grow = base + g * 16 + l4 * 4 + q;
                if (grow < M) {
                    int d = 0;
                    if (MSG_ATOMIC) d = dstIdx[grow];
#pragma unroll
                    for (int nf = 0; nf < 4; ++nf) {
                        const int col = nf * 16 + l15;
                        const float v = acc3[g][nf][q];
                        out[(size_t)grow * 64 + col] = v;
                        if constexpr (MSG_ATOMIC)
                            atomicAdd(msgs_out + (size_t)d * 64 + col, v);
                    }
                }
            }

        // rotate prefetched indices
#pragma unroll
        for (int g = 0; g < 2; ++g) {
            cig[g] = nig[g]; cis[g] = nis[g]; cid[g] = nid[g];
            cgs[g] = ngs[g]; cge[g] = nge[g];
        }
        if (base + bstride >= ((M + 255) & ~255)) break;
    }

    // ---- comb flush: registers -> own Hs slice -> cross-wave tree ----
#pragma unroll
    for (int nf = 0; nf < 4; ++nf)
#pragma unroll
        for (int q = 0; q < 4; ++q)
            ((float*)Hs)[(l4 * 4 + q) * 64 + nf * 16 + l15] = acc_comb[nf][q];
    __syncthreads();
    float* hbase = (float*)(lds + HOFF);
    float* rep = comb_rep + (size_t)(blockIdx.x & 63) * 1024;
    for (int i = t; i < 1024; i += 512) {
        float s = 0.f;
#pragma unroll
        for (int wv = 0; wv < 8; ++wv) s += hbase[wv * 2048 + i];
        atomicAdd(rep + i, s);
    }
}

// ---------------------------------------------------------------------------
__global__ __launch_bounds__(256)
void reduce_rep_kernel(const float* __restrict__ rep, float* __restrict__ outv)
{
    const int s = blockIdx.x * 256 + threadIdx.x;   // 0..2047
    const int arr = s >> 10, idx = s & 1023;
    const float* p = rep + (size_t)arr * 65536 + idx;
    float v = 0.f;
#pragma unroll 8
    for (int r = 0; r < 64; ++r) v += p[(size_t)r * 1024];
    outv[s] = v;
}

// ---------------------------------------------------------------------------
__global__ __launch_bounds__(256)
void u_kernel(const float* __restrict__ ncomb, const float* __restrict__ ecomb,
              const float* __restrict__ gr,
              const float* __restrict__ W1, const float* __restrict__ b1,
              const float* __restrict__ W2, const float* __restrict__ b2,
              const float* __restrict__ W3, const float* __restrict__ b3,
              float* uout)
{
    __shared__ float X[16 * 192];
    __shared__ float Hs[16 * 128];
    __shared__ float H2s[16 * 128];
    const int t = threadIdx.x;
#pragma unroll
    for (int i = 0; i < 12; ++i) {
        const int idx = i * 256 + t;
        const int g = idx / 192, col = idx % 192;
        float v;
        if      (col < 64)  v = ncomb[g * 64 + col];
        else if (col < 128) v = ecomb[g * 64 + col - 64];
        else                v = gr[g * 64 + col - 128];
        X[idx] = v;
    }
    __syncthreads();
    {
        const int j = t & 127, gb = t >> 7;
        float a[8];
#pragma unroll
        for (int gi = 0; gi < 8; ++gi) a[gi] = b1[j];
        for (int k = 0; k < 192; ++k) {
            const float wv = W1[k * 128 + j];
#pragma unroll
            for (int gi = 0; gi < 8; ++gi) a[gi] += X[(gb + gi * 2) * 192 + k] * wv;
        }
#pragma unroll
        for (int gi = 0; gi < 8; ++gi) Hs[(gb + gi * 2) * 128 + j] = fmaxf(a[gi], 0.f);
    }
    __syncthreads();
    {
        const int j = t & 127, gb = t >> 7;
        float a[8];
#pragma unroll
        for (int gi = 0; gi < 8; ++gi) a[gi] = b2[j];
        for (int k = 0; k < 128; ++k) {
            const float wv = W2[k * 128 + j];
#pragma unroll
            for (int gi = 0; gi < 8; ++gi) a[gi] += Hs[(gb + gi * 2) * 128 + k] * wv;
        }
#pragma unroll
        for (int gi = 0; gi < 8; ++gi) H2s[(gb + gi * 2) * 128 + j] = fmaxf(a[gi], 0.f);
    }
    __syncthreads();
    {
        const int j = t & 63, gb = t >> 6;
        float a[4];
#pragma unroll
        for (int gi = 0; gi < 4; ++gi) a[gi] = b3[j];
        for (int k = 0; k < 128; ++k) {
            const float wv = W3[k * 64 + j];
#pragma unroll
            for (int gi = 0; gi < 4; ++gi) a[gi] += H2s[(gb + gi * 4) * 128 + k] * wv;
        }
#pragma unroll
        for (int gi = 0; gi < 4; ++gi) uout[(gb + gi * 4) * 64 + j] = a[gi];
    }
}

// ---------------------------------------------------------------------------
extern "C" void kernel_launch(void* const* d_in, const int* in_sizes, int n_in,
                              void* d_out, int out_size, void* d_ws, size_t ws_size,
                              hipStream_t stream)
{
    const float* edge_feat = (const float*)d_in[0];
    const float* node_feat = (const float*)d_in[1];
    const float* g_repr    = (const float*)d_in[2];
    const int*   src       = (const int*)d_in[3];
    const int*   dst       = (const int*)d_in[4];
    const int*   e2g       = (const int*)d_in[5];
    const int*   n2g       = (const int*)d_in[6];
    const float* We1 = (const float*)d_in[7];  const float* be1 = (const float*)d_in[8];
    const float* We2 = (const float*)d_in[9];  const float* be2 = (const float*)d_in[10];
    const float* We3 = (const float*)d_in[11]; const float* be3 = (const float*)d_in[12];
    const float* Wn1 = (const float*)d_in[13]; const float* bn1 = (const float*)d_in[14];
    const float* Wn2 = (const float*)d_in[15]; const float* bn2 = (const float*)d_in[16];
    const float* Wn3 = (const float*)d_in[17]; const float* bn3 = (const float*)d_in[18];
    const float* Wu1 = (const float*)d_in[19]; const float* bu1 = (const float*)d_in[20];
    const float* Wu2 = (const float*)d_in[21]; const float* bu2 = (const float*)d_in[22];
    const float* Wu3 = (const float*)d_in[23]; const float* bu3 = (const float*)d_in[24];

    const int E = in_sizes[3];   // 400000
    const int N = in_sizes[6];   // 50000

    float* e_out = (float*)d_out;
    float* n_out = e_out + (size_t)E * 64;
    float* u_out = n_out + (size_t)N * 64;

    // ws layout: 0 ecomb_rep 256K | 262144 ncomb_rep 256K | 524288 ecomb|ncomb
    // 532480 wf: edge 96K | node 80K @+98304 | Ge 8K @+180224 | Gn 8K @+188416
    // 745472 deg | 945472 start | 1145472 cursor | 1345472 psum | 1346496 elist
    char* wsc = (char*)d_ws;
    float* ecomb_rep = (float*)wsc;
    float* ncomb_rep = (float*)(wsc + 262144);
    float* ecomb     = (float*)(wsc + 524288);
    float* ncomb     = ecomb + 1024;
    char*  wf        = wsc + 532480;
    const char* WEsrc = wf;
    const char* WNsrc = wf + 98304;
    const char* Gef   = wf + 180224;
    const char* Gnf   = wf + 188416;
    int* deg    = (int*)(wsc + 745472);
    int* startA = (int*)(wsc + 945472);
    int* cursor = (int*)(wsc + 1145472);
    int* psum   = (int*)(wsc + 1345472);
    int* elist  = (int*)(wsc + 1346496);
    const size_t WS_NEED = 1346496 + (size_t)E * 4;
    const bool csr = (ws_size >= WS_NEED);

    constexpr int SH_E = 98304 + 65536;   // 160 KB
    constexpr int SH_N = 81920 + 65536;   // 144 KB

    hipMemsetAsync(wsc, 0, 524288, stream);
    prep_weights<<<44, 256, 0, stream>>>(We1, We2, We3, Wn1, Wn2, Wn3, wf);
    prep_g<<<4, 256, 0, stream>>>(g_repr, We1, be1, Wn1, bn1, wf + 180224);

    const int etiles = (E + 255) / 256;
    const int ntiles = (N + 255) / 256;
    (void)etiles; (void)ntiles;

    if (csr) {
        hipMemsetAsync(deg, 0, (size_t)N * 4, stream);
        const int EB = (E + 255) / 256;
        const int NB = (N + 255) / 256;
        hist_kernel <<<EB, 256, 0, stream>>>(dst, deg, E);
        scanA_kernel<<<NB, 256, 0, stream>>>(deg, psum, N);
        scanB_kernel<<<1, 256, 0, stream>>>(psum, NB);
        scanC_kernel<<<NB, 256, 0, stream>>>(deg, psum, startA, cursor, N);
        fill_kernel <<<EB, 256, 0, stream>>>(dst, cursor, elist, E);

        auto ek = mlp_v12_kernel<3, true, false, false>;
        auto nk = mlp_v12_kernel<2, false, false, true>;
        hipFuncSetAttribute((const void*)ek,
                            hipFuncAttributeMaxDynamicSharedMemorySize, SH_E);
        hipFuncSetAttribute((const void*)nk,
                            hipFuncAttributeMaxDynamicSharedMemorySize, SH_N);

        ek<<<256, 512, SH_E, stream>>>(
            edge_feat, node_feat, src, dst, e2g,
            nullptr, nullptr, nullptr, nullptr,
            WEsrc, Gef, be2, be3, e_out, nullptr, ecomb_rep, E, etiles);
        nk<<<256, 512, SH_N, stream>>>(
            node_feat, nullptr, nullptr, nullptr, n2g,
            startA, cursor, elist, e_out,
            WNsrc, Gnf, bn2, bn3, n_out, nullptr, ncomb_rep, N, ntiles);
    } else {
        hipMemsetAsync(n_out, 0, (size_t)N * 64 * sizeof(float), stream);
        auto ek = mlp_v12_kernel<3, true, true, false>;
        auto nk = mlp_v12_kernel<2, false, false, false>;
        hipFuncSetAttribute((const void*)ek,
                            hipFuncAttributeMaxDynamicSharedMemorySize, SH_E);
        hipFuncSetAttribute((const void*)nk,
                            hipFuncAttributeMaxDynamicSharedMemorySize, SH_N);
        ek<<<256, 512, SH_E, stream>>>(
            edge_feat, node_feat, src, dst, e2g,
            nullptr, nullptr, nullptr, nullptr,
            WEsrc, Gef, be2, be3, e_out, n_out, ecomb_rep, E, etiles);
        nk<<<256, 512, SH_N, stream>>>(
            node_feat, n_out, nullptr, nullptr, n2g,
            nullptr, nullptr, nullptr, nullptr,
            WNsrc, Gnf, bn2, bn3, n_out, nullptr, ncomb_rep, N, ntiles);
    }

    reduce_rep_kernel<<<8, 256, 0, stream>>>(ecomb_rep, ecomb);
    u_kernel<<<1, 256, 0, stream>>>(ncomb, ecomb, g_repr,
                                    Wu1, bu1, Wu2, bu2, Wu3, bu3, u_out);
}